// Round 1
// 6854.527 us; speedup vs baseline: 4.4011x; 4.4011x over previous
//
#include <hip/hip_runtime.h>
#include <hip/hip_bf16.h>
#include <cmath>

#define DIMC 192
#define NHEAD 6
#define HDIM 32
#define TDIM 128
#define HIDC 510
#define HID2C 1020
#define REDC 24
#define NB 4
#define NH 256
#define NW 256
#define HW 65536
#define NPB (DIMC*HW)
#define STRIP 16
#define TROWS 18

typedef unsigned short u16;

__device__ __forceinline__ float bf2f(u16 u){
  union { unsigned int i; float f; } v; v.i = ((unsigned int)u) << 16; return v.f;
}
__device__ __forceinline__ u16 f2bf(float f){
  union { float f; unsigned int i; } v; v.f = f;
  unsigned int i = v.i;
  return (u16)((i + 0x7FFFu + ((i >> 16) & 1u)) >> 16);
}

// ---------- transpose pin_w / pout_w to [c][o] layouts ----------
__global__ __launch_bounds__(256) void k_prep(const float* __restrict__ pin_w,
    const float* __restrict__ pout_w, float* __restrict__ pin_wT, float* __restrict__ pout_wT)
{
  int i = blockIdx.x*256 + threadIdx.x;
  if (i < HID2C*DIMC){ int o = i / DIMC, c = i % DIMC; pin_wT[(size_t)c*HID2C + o] = pin_w[i]; }
  if (i < DIMC*HIDC){ int o = i / HIDC, c = i % HIDC; pout_wT[(size_t)c*DIMC + o] = pout_w[i]; }
}

// ---------- per-batch sum/sumsq over x ----------
__global__ __launch_bounds__(256) void k_reduce(const float* __restrict__ x,
    double* __restrict__ sum, double* __restrict__ sq)
{
  int b = blockIdx.y;
  const float4* xb = (const float4*)(x + (size_t)b*NPB);
  float ls = 0.f, lq = 0.f;
  int n4 = NPB/4;
  for (int i = blockIdx.x*256 + threadIdx.x; i < n4; i += gridDim.x*256){
    float4 u = xb[i];
    ls += u.x+u.y+u.z+u.w; lq += u.x*u.x + u.y*u.y + u.z*u.z + u.w*u.w;
  }
  __shared__ float rs_[256], rq_[256];
  int tid = threadIdx.x;
  rs_[tid]=ls; rq_[tid]=lq; __syncthreads();
  for (int st=128; st>0; st>>=1){ if (tid<st){ rs_[tid]+=rs_[tid+st]; rq_[tid]+=rq_[tid+st]; } __syncthreads(); }
  if (tid==0){ atomicAdd(&sum[b], (double)rs_[0]); atomicAdd(&sq[b], (double)rq_[0]); }
}

__global__ void k_stats(const double* __restrict__ sum, const double* __restrict__ sq,
                        float* __restrict__ stats)
{
  int t = threadIdx.x;
  if (t < NB){
    double mu = sum[t] / (double)NPB;
    double var = sq[t] / (double)NPB - mu*mu;
    stats[2*t]   = (float)mu;
    stats[2*t+1] = (float)(1.0 / sqrt(var + 1e-5));
  }
}

// ---------- s = silu(temb@w1+b1)@w2+b2 ----------
__global__ __launch_bounds__(256) void k_svec(const float* __restrict__ temb,
    const float* __restrict__ w1, const float* __restrict__ b1,
    const float* __restrict__ w2, const float* __restrict__ b2, float* __restrict__ s)
{
  __shared__ float te[NB*TDIM];
  __shared__ float hid[NB*TDIM];
  int tid = threadIdx.x;
  for (int i = tid; i < NB*TDIM; i += 256) te[i] = temb[i];
  __syncthreads();
  for (int i = tid; i < NB*TDIM; i += 256){
    int b = i >> 7, j = i & 127;
    float a = b1[j];
    for (int c = 0; c < TDIM; c++) a += te[b*TDIM + c]*w1[c*TDIM + j];
    hid[i] = a / (1.f + expf(-a));
  }
  __syncthreads();
  for (int i = tid; i < NB*4*DIMC; i += 256){
    int b = i / 768, o = i % 768;
    float a = b2[o];
    for (int c = 0; c < TDIM; c++) a += hid[b*TDIM + c]*w2[c*768 + o];
    s[i] = a;
  }
}

// ---------- window attention with fused gn1+adawm on load ----------
// writes x1 = x + attn, accumulates gn2 stats
// LDS plan (48.6 KB total -> 3 blocks/CU):
//   qkvbuf [16*577] fp32 : qkv matrix; reused as rs_/rq_ reduction scratch in epilogue
//   xabuf  [3200]   fp32 : xw [c][t] during load/qkv phase; reused as ao [t][c] pitch 200
__global__ __launch_bounds__(256) void k_attn(
    const float* __restrict__ x0,
    const float* __restrict__ stats, const float* __restrict__ gg, const float* __restrict__ gb,
    const float* __restrict__ sv,
    const float* __restrict__ qkv_w, const float* __restrict__ qkv_b,
    const float* __restrict__ proj_w, const float* __restrict__ proj_b,
    float* __restrict__ x1out, double* __restrict__ gn2_sum, double* __restrict__ gn2_sq)
{
  __shared__ float qkvbuf[16*577];
  __shared__ float xabuf[3200];

  float* xw  = xabuf;          // [c][t], 3072 floats (dead after qkv phase)
  float* ao  = xabuf;          // [t][c] pitch 200, 3200 floats (written after barrier)
  float* qkv = qkvbuf;         // [t][o] pitch 577
  float* rs_ = qkvbuf;         // epilogue reduction (qkv dead by then)
  float* rq_ = qkvbuf + 256;

  int tid = threadIdx.x;
  int blk = blockIdx.x;
  int b  = blk >> 12;
  int wy = (blk >> 6) & 63;
  int wx = blk & 63;

  float mu = stats[2*b], rstd = stats[2*b+1];
  const float* sb = sv + b*768;

  // load 4x4 window as 4 quads/channel, apply gn1 + adawm inline
  for (int l = tid; l < DIMC*4; l += 256){
    int c = l >> 2, q = l & 3;
    int qy = q >> 1, qx = q & 1;
    const float* p = x0 + ((size_t)(b*DIMC + c)*NH + (wy*4 + qy*2))*NW + wx*4 + qx*2;
    float2 t0 = *(const float2*)p;
    float2 t1 = *(const float2*)(p + NW);
    float gc = gg[c], bc = gb[c];
    float n00 = (t0.x-mu)*rstd*gc + bc;
    float n01 = (t0.y-mu)*rstd*gc + bc;
    float n10 = (t1.x-mu)*rstd*gc + bc;
    float n11 = (t1.y-mu)*rstd*gc + bc;
    float ll = (n00+n01+n10+n11)*0.5f*sb[c];
    float hl = (n00-n10+n01-n11)*0.5f*sb[192+c];
    float lh = (n00+n10-n01-n11)*0.5f*sb[384+c];
    float hh = (n00-n10-n01+n11)*0.5f*sb[576+c];
    float* d = &xw[c*16 + qy*8 + qx*2];
    d[0] = (ll+hl+lh+hh)*0.5f;
    d[1] = (ll+hl-lh-hh)*0.5f;
    d[4] = (ll-hl+lh-hh)*0.5f;
    d[5] = (ll-hl-lh+hh)*0.5f;
  }
  __syncthreads();

  if (tid < 192){
    // qkv: thread owns output columns o = tid, tid+192, tid+384 (static trip count 3
    // -> acc stays in VGPRs; the old runtime-bound k-loop spilled acc[3][16] to scratch)
    float acc[3][16];
    #pragma unroll
    for (int k = 0; k < 3; k++)
      #pragma unroll
      for (int t = 0; t < 16; t++) acc[k][t] = 0.f;
    const float* wp = qkv_w + tid;
    for (int c = 0; c < DIMC; c++){
      float xv[16];
      #pragma unroll
      for (int t = 0; t < 16; t++) xv[t] = xw[c*16 + t];
      #pragma unroll
      for (int k = 0; k < 3; k++){
        float w = wp[c*576 + 192*k];
        #pragma unroll
        for (int t = 0; t < 16; t++) acc[k][t] += xv[t] * w;
      }
    }
    #pragma unroll
    for (int k = 0; k < 3; k++){
      int o = tid + 192*k;
      float bq = qkv_b[o];
      #pragma unroll
      for (int t = 0; t < 16; t++) qkv[t*577 + o] = acc[k][t] + bq;
    }
  }
  __syncthreads();

  if (tid < 96){
    int h = tid >> 4, q = tid & 15;
    float sc[16]; float mx = -1e30f;
    for (int kt = 0; kt < 16; kt++){
      float d = 0.f;
      #pragma unroll
      for (int e = 0; e < HDIM; e++)
        d += qkv[q*577 + h*HDIM + e] * qkv[kt*577 + 192 + h*HDIM + e];
      d *= 0.17677669529663687f;
      sc[kt] = d; mx = fmaxf(mx, d);
    }
    float sum = 0.f;
    for (int kt = 0; kt < 16; kt++){ float e = expf(sc[kt]-mx); sc[kt]=e; sum+=e; }
    float inv = 1.f/sum;
    for (int e = 0; e < HDIM; e++){
      float a = 0.f;
      for (int kt = 0; kt < 16; kt++) a += sc[kt]*qkv[kt*577 + 384 + h*HDIM + e];
      ao[q*200 + h*HDIM + e] = a*inv;
    }
  }
  __syncthreads();

  float lsum = 0.f, lsq = 0.f;
  if (tid < DIMC){
    int o = tid;
    float acc[16];
    float pb = proj_b[o];
    #pragma unroll
    for (int t = 0; t < 16; t++) acc[t] = pb;
    for (int c = 0; c < DIMC; c++){
      float w = proj_w[c*DIMC + o];
      #pragma unroll
      for (int t = 0; t < 16; t++) acc[t] += ao[t*200 + c]*w;
    }
    #pragma unroll
    for (int t4 = 0; t4 < 4; t4++){
      int y = wy*4 + t4;
      size_t addr = ((size_t)(b*DIMC + o)*NH + y)*NW + wx*4;
      float4 xv = *(const float4*)&x0[addr];
      float4 ov;
      ov.x = xv.x + acc[t4*4+0];
      ov.y = xv.y + acc[t4*4+1];
      ov.z = xv.z + acc[t4*4+2];
      ov.w = xv.w + acc[t4*4+3];
      *(float4*)&x1out[addr] = ov;
      lsum += ov.x+ov.y+ov.z+ov.w;
      lsq  += ov.x*ov.x + ov.y*ov.y + ov.z*ov.z + ov.w*ov.w;
    }
  }
  rs_[tid] = lsum; rq_[tid] = lsq;
  __syncthreads();
  for (int st = 128; st > 0; st >>= 1){
    if (tid < st){ rs_[tid] += rs_[tid+st]; rq_[tid] += rq_[tid+st]; }
    __syncthreads();
  }
  if (tid == 0){
    atomicAdd(&gn2_sum[b], (double)rs_[0]);
    atomicAdd(&gn2_sq[b], (double)rq_[0]);
  }
}

// ---------- gdfn stage 1: fused gn2+adawm + pointwise 192->1020 into strip buffer T (bf16)
__global__ __launch_bounds__(256) void k_pin(
    const float* __restrict__ x1, const float* __restrict__ stats,
    const float* __restrict__ gg, const float* __restrict__ gb, const float* __restrict__ sv,
    const float* __restrict__ pin_wT, const float* __restrict__ pin_b,
    u16* __restrict__ T, int s)
{
  __shared__ float px[DIMC*16]; // [c][p]
  int tid = threadIdx.x;
  int xc = blockIdx.x, r = blockIdx.y, b = blockIdx.z;
  int y = s*STRIP - 1 + r;
  int x0 = xc*16;
  u16* Trow = T + ((size_t)(b*TROWS + r)*NW + x0)*HID2C;
  bool valid = (y >= 0) && (y < NH);
  if (!valid){
    for (int l = tid; l < 16*HID2C; l += 256) Trow[l] = 0;
    return;
  }
  float mu = stats[2*b], rstd = stats[2*b+1];
  const float* sb = sv + b*768;
  int ytop = y & ~1;
  bool istop = (y == ytop);
  for (int l = tid; l < DIMC*8; l += 256){
    int c = l >> 3, u = l & 7;
    const float* p = x1 + ((size_t)(b*DIMC + c)*NH + ytop)*NW + x0 + 2*u;
    float2 t0 = *(const float2*)p;
    float2 t1 = *(const float2*)(p + NW);
    float gc = gg[c], bc = gb[c];
    float n00 = (t0.x-mu)*rstd*gc + bc;
    float n01 = (t0.y-mu)*rstd*gc + bc;
    float n10 = (t1.x-mu)*rstd*gc + bc;
    float n11 = (t1.y-mu)*rstd*gc + bc;
    float ll = (n00+n01+n10+n11)*0.5f*sb[c];
    float hl = (n00-n10+n01-n11)*0.5f*sb[192+c];
    float lh = (n00+n10-n01-n11)*0.5f*sb[384+c];
    float hh = (n00-n10-n01+n11)*0.5f*sb[576+c];
    float v0, v1;
    if (istop){ v0 = (ll+hl+lh+hh)*0.5f; v1 = (ll+hl-lh-hh)*0.5f; }
    else      { v0 = (ll-hl+lh-hh)*0.5f; v1 = (ll-hl-lh+hh)*0.5f; }
    px[c*16 + 2*u]     = v0;
    px[c*16 + 2*u + 1] = v1;
  }
  __syncthreads();
  if (tid < 255){
    int o4 = tid*4;
    float4 bi = *(const float4*)&pin_b[o4];
    float acc[16][4];
    #pragma unroll
    for (int p = 0; p < 16; p++){ acc[p][0]=bi.x; acc[p][1]=bi.y; acc[p][2]=bi.z; acc[p][3]=bi.w; }
    for (int c = 0; c < DIMC; c++){
      float4 w = *(const float4*)&pin_wT[(size_t)c*HID2C + o4];
      #pragma unroll
      for (int p = 0; p < 16; p++){
        float xv = px[c*16 + p];
        acc[p][0] += xv*w.x; acc[p][1] += xv*w.y; acc[p][2] += xv*w.z; acc[p][3] += xv*w.w;
      }
    }
    for (int p = 0; p < 16; p++){
      ushort4 o; o.x=f2bf(acc[p][0]); o.y=f2bf(acc[p][1]); o.z=f2bf(acc[p][2]); o.w=f2bf(acc[p][3]);
      *(ushort4*)&Trow[(size_t)p*HID2C + o4] = o;
    }
  }
}

// ---------- gdfn stage 2: depthwise 3x3 + gelu-gate + pointwise 510->192 (channel-major G bf16)
__global__ __launch_bounds__(256) void k_dwgate(
    const u16* __restrict__ T, const float* __restrict__ pout_wT,
    const float* __restrict__ dw_w, const float* __restrict__ dw_b,
    const float* __restrict__ pout_b, u16* __restrict__ G,
    double* __restrict__ se_sum, int s)
{
  __shared__ float g[16][512];
  int tid = threadIdx.x;
  int xc = blockIdx.x, ry = blockIdx.y, b = blockIdx.z;
  int y = s*STRIP + ry;
  int x0 = xc*16;
  int r = ry + 1;
  if (tid < 255){
    for (int k = 0; k < 2; k++){
      int ch = 2*tid + k;
      int ch2 = ch + HIDC;
      float w1[9], w2[9];
      #pragma unroll
      for (int t9 = 0; t9 < 9; t9++){ w1[t9] = dw_w[ch*9+t9]; w2[t9] = dw_w[ch2*9+t9]; }
      float db1 = dw_b[ch], db2 = dw_b[ch2];
      for (int p = 0; p < 16; p++){
        int gx = x0 + p;
        float a1 = db1, a2 = db2;
        for (int dy = -1; dy <= 1; dy++){
          const u16* Tr = T + (size_t)(b*TROWS + r + dy)*NW*HID2C;
          for (int dx = -1; dx <= 1; dx++){
            int xx = gx + dx;
            if (xx < 0 || xx >= NW) continue;
            int wi = (dy+1)*3 + (dx+1);
            a1 += w1[wi]*bf2f(Tr[(size_t)xx*HID2C + ch]);
            a2 += w2[wi]*bf2f(Tr[(size_t)xx*HID2C + ch2]);
          }
        }
        float ge = 0.5f*a1*(1.f + erff(a1*0.70710678118654752f));
        g[p][ch] = ge*a2;
      }
    }
  }
  __syncthreads();
  if (tid < DIMC){
    int o = tid;
    float pb = pout_b[o];
    float acc[16];
    #pragma unroll
    for (int p = 0; p < 16; p++) acc[p] = pb;
    for (int c = 0; c < HIDC; c++){
      float w = pout_wT[(size_t)c*DIMC + o];
      #pragma unroll
      for (int p = 0; p < 16; p++) acc[p] += g[p][c]*w;
    }
    float lsum = 0.f;
    u16* Gp = G + ((size_t)(b*DIMC + o)*NH + y)*NW + x0;
    #pragma unroll
    for (int q4 = 0; q4 < 4; q4++){
      ushort4 ov;
      ov.x = f2bf(acc[q4*4+0]); ov.y = f2bf(acc[q4*4+1]);
      ov.z = f2bf(acc[q4*4+2]); ov.w = f2bf(acc[q4*4+3]);
      *(ushort4*)&Gp[q4*4] = ov;
    }
    #pragma unroll
    for (int p = 0; p < 16; p++) lsum += acc[p];
    atomicAdd(&se_sum[b*DIMC + o], (double)lsum);
  }
}

// ---------- SE gate vector ----------
__global__ __launch_bounds__(256) void k_se(const double* __restrict__ se_sum,
    const float* __restrict__ w1, const float* __restrict__ w2, float* __restrict__ sey)
{
  __shared__ float mean[NB*DIMC];
  __shared__ float hid[NB*REDC];
  int tid = threadIdx.x;
  for (int i = tid; i < NB*DIMC; i += 256) mean[i] = (float)(se_sum[i] * (1.0/(double)HW));
  __syncthreads();
  for (int i = tid; i < NB*REDC; i += 256){
    int b = i / REDC, rr = i % REDC;
    float a = 0.f;
    for (int c = 0; c < DIMC; c++) a += mean[b*DIMC + c]*w1[c*REDC + rr];
    hid[i] = fmaxf(a, 0.f);
  }
  __syncthreads();
  for (int i = tid; i < NB*DIMC; i += 256){
    int b = i / DIMC, o = i % DIMC;
    float a = 0.f;
    for (int rr = 0; rr < REDC; rr++) a += hid[b*REDC + rr]*w2[rr*DIMC + o];
    sey[i] = 1.f/(1.f + expf(-a));
  }
}

// ---------- final: out = x1 + G * sey  (channel-major, float4 RMW) ----------
__global__ __launch_bounds__(256) void k_final(const u16* __restrict__ G,
    const float* __restrict__ sey, float* __restrict__ xout)
{
  int i4 = blockIdx.x*256 + threadIdx.x;
  int cpix = i4 >> 14;              // b*DIMC + c
  float sc = sey[cpix];
  ushort4 gv = *(const ushort4*)&G[(size_t)i4*4];
  float4 xv = *(const float4*)&xout[(size_t)i4*4];
  float4 ov;
  ov.x = xv.x + bf2f(gv.x)*sc;
  ov.y = xv.y + bf2f(gv.y)*sc;
  ov.z = xv.z + bf2f(gv.z)*sc;
  ov.w = xv.w + bf2f(gv.w)*sc;
  *(float4*)&xout[(size_t)i4*4] = ov;
}

extern "C" void kernel_launch(void* const* d_in, const int* in_sizes, int n_in,
                              void* d_out, int out_size, void* d_ws, size_t ws_size,
                              hipStream_t stream)
{
  const float* x      = (const float*)d_in[0];
  const float* temb   = (const float*)d_in[1];
  const float* gn1_g  = (const float*)d_in[2];
  const float* gn1_b  = (const float*)d_in[3];
  const float* aw1_w1 = (const float*)d_in[4];
  const float* aw1_b1 = (const float*)d_in[5];
  const float* aw1_w2 = (const float*)d_in[6];
  const float* aw1_b2 = (const float*)d_in[7];
  const float* qkv_w  = (const float*)d_in[8];
  const float* qkv_b  = (const float*)d_in[9];
  const float* proj_w = (const float*)d_in[10];
  const float* proj_b = (const float*)d_in[11];
  const float* gn2_g  = (const float*)d_in[12];
  const float* gn2_b  = (const float*)d_in[13];
  const float* aw2_w1 = (const float*)d_in[14];
  const float* aw2_b1 = (const float*)d_in[15];
  const float* aw2_w2 = (const float*)d_in[16];
  const float* aw2_b2 = (const float*)d_in[17];
  const float* pin_w  = (const float*)d_in[18];
  const float* pin_b  = (const float*)d_in[19];
  const float* dw_w   = (const float*)d_in[20];
  const float* dw_b   = (const float*)d_in[21];
  const float* pout_w = (const float*)d_in[22];
  const float* pout_b = (const float*)d_in[23];
  const float* se_w1  = (const float*)d_in[24];
  const float* se_w2  = (const float*)d_in[25];

  unsigned char* ws = (unsigned char*)d_ws;
  size_t nElem = (size_t)NB*DIMC*HW;                       // 50331648
  u16* G  = (u16*)ws;                                      // gdfn out, channel-major bf16 (100.7 MB)
  u16* Tb = (u16*)(ws + nElem*2);                          // pin strip buffer bf16 (37.6 MB)
  size_t offD = nElem*2 + (size_t)NB*TROWS*NW*HID2C*2;
  double* gn1_sum = (double*)(ws + offD);
  double* gn1_sq  = gn1_sum + 4;
  double* gn2_sum = gn1_sum + 8;
  double* gn2_sq  = gn1_sum + 12;
  double* se_sum  = gn1_sum + 16;                          // 768 doubles
  float* fbase  = (float*)(ws + offD + 784*8);
  float* s1     = fbase;
  float* s2     = s1 + 3072;
  float* stats1 = s2 + 3072;
  float* stats2 = stats1 + 8;
  float* sey    = stats2 + 8;
  float* pin_wT  = sey + 768;                              // 192x1020 fp32
  float* pout_wT = pin_wT + (size_t)HID2C*DIMC;            // 510x192 fp32

  float* x1 = (float*)d_out;

  hipMemsetAsync(ws + offD, 0, 784*8, stream);
  k_prep<<<765, 256, 0, stream>>>(pin_w, pout_w, pin_wT, pout_wT);
  k_reduce<<<dim3(1024,4), 256, 0, stream>>>(x, gn1_sum, gn1_sq);
  k_stats<<<1, 64, 0, stream>>>(gn1_sum, gn1_sq, stats1);
  k_svec<<<1, 256, 0, stream>>>(temb, aw1_w1, aw1_b1, aw1_w2, aw1_b2, s1);
  k_svec<<<1, 256, 0, stream>>>(temb, aw2_w1, aw2_b1, aw2_w2, aw2_b2, s2);
  k_attn<<<16384, 256, 0, stream>>>(x, stats1, gn1_g, gn1_b, s1,
                                    qkv_w, qkv_b, proj_w, proj_b, x1, gn2_sum, gn2_sq);
  k_stats<<<1, 64, 0, stream>>>(gn2_sum, gn2_sq, stats2);
  for (int s = 0; s < 16; s++){
    k_pin<<<dim3(16, TROWS, 4), 256, 0, stream>>>(x1, stats2, gn2_g, gn2_b, s2,
                                                  pin_wT, pin_b, Tb, s);
    k_dwgate<<<dim3(16, STRIP, 4), 256, 0, stream>>>(Tb, pout_wT, dw_w, dw_b, pout_b, G, se_sum, s);
  }
  k_se<<<1, 256, 0, stream>>>(se_sum, se_w1, se_w2, sey);
  k_final<<<49152, 256, 0, stream>>>(G, sey, x1);
}

// Round 2
// 5166.557 us; speedup vs baseline: 5.8390x; 1.3267x over previous
//
#include <hip/hip_runtime.h>
#include <hip/hip_bf16.h>
#include <cmath>

#define DIMC 192
#define NHEAD 6
#define HDIM 32
#define TDIM 128
#define HIDC 510
#define HID2C 1020
#define REDC 24
#define NB 4
#define NH 256
#define NW 256
#define HW 65536
#define NPB (DIMC*HW)

typedef unsigned short u16;

__device__ __forceinline__ float bf2f(u16 u){
  union { unsigned int i; float f; } v; v.i = ((unsigned int)u) << 16; return v.f;
}
__device__ __forceinline__ u16 f2bf(float f){
  union { float f; unsigned int i; } v; v.f = f;
  unsigned int i = v.i;
  return (u16)((i + 0x7FFFu + ((i >> 16) & 1u)) >> 16);
}
// XCD-chunked bijective swizzle (requires gridDim.x % 8 == 0)
__device__ __forceinline__ int xcd_swz(){
  int n = gridDim.x, l = blockIdx.x;
  return (l & 7)*(n >> 3) + (l >> 3);
}

// ---------- transpose pin_w / pout_w to [c][o] layouts ----------
__global__ __launch_bounds__(256) void k_prep(const float* __restrict__ pin_w,
    const float* __restrict__ pout_w, float* __restrict__ pin_wT, float* __restrict__ pout_wT)
{
  int i = blockIdx.x*256 + threadIdx.x;
  if (i < HID2C*DIMC){ int o = i / DIMC, c = i % DIMC; pin_wT[(size_t)c*HID2C + o] = pin_w[i]; }
  if (i < DIMC*HIDC){ int o = i / HIDC, c = i % HIDC; pout_wT[(size_t)c*DIMC + o] = pout_w[i]; }
}

// ---------- per-batch sum/sumsq over x ----------
__global__ __launch_bounds__(256) void k_reduce(const float* __restrict__ x,
    double* __restrict__ sum, double* __restrict__ sq)
{
  int b = blockIdx.y;
  const float4* xb = (const float4*)(x + (size_t)b*NPB);
  float ls = 0.f, lq = 0.f;
  int n4 = NPB/4;
  for (int i = blockIdx.x*256 + threadIdx.x; i < n4; i += gridDim.x*256){
    float4 u = xb[i];
    ls += u.x+u.y+u.z+u.w; lq += u.x*u.x + u.y*u.y + u.z*u.z + u.w*u.w;
  }
  __shared__ float rs_[256], rq_[256];
  int tid = threadIdx.x;
  rs_[tid]=ls; rq_[tid]=lq; __syncthreads();
  for (int st=128; st>0; st>>=1){ if (tid<st){ rs_[tid]+=rs_[tid+st]; rq_[tid]+=rq_[tid+st]; } __syncthreads(); }
  if (tid==0){ atomicAdd(&sum[b], (double)rs_[0]); atomicAdd(&sq[b], (double)rq_[0]); }
}

__global__ void k_stats(const double* __restrict__ sum, const double* __restrict__ sq,
                        float* __restrict__ stats)
{
  int t = threadIdx.x;
  if (t < NB){
    double mu = sum[t] / (double)NPB;
    double var = sq[t] / (double)NPB - mu*mu;
    stats[2*t]   = (float)mu;
    stats[2*t+1] = (float)(1.0 / sqrt(var + 1e-5));
  }
}

// ---------- s = silu(temb@w1+b1)@w2+b2 ----------
__global__ __launch_bounds__(256) void k_svec(const float* __restrict__ temb,
    const float* __restrict__ w1, const float* __restrict__ b1,
    const float* __restrict__ w2, const float* __restrict__ b2, float* __restrict__ s)
{
  __shared__ float te[NB*TDIM];
  __shared__ float hid[NB*TDIM];
  int tid = threadIdx.x;
  for (int i = tid; i < NB*TDIM; i += 256) te[i] = temb[i];
  __syncthreads();
  for (int i = tid; i < NB*TDIM; i += 256){
    int b = i >> 7, j = i & 127;
    float a = b1[j];
    for (int c = 0; c < TDIM; c++) a += te[b*TDIM + c]*w1[c*TDIM + j];
    hid[i] = a / (1.f + expf(-a));
  }
  __syncthreads();
  for (int i = tid; i < NB*4*DIMC; i += 256){
    int b = i / 768, o = i % 768;
    float a = b2[o];
    for (int c = 0; c < TDIM; c++) a += hid[b*TDIM + c]*w2[c*768 + o];
    s[i] = a;
  }
}

// ---------- window attention with fused gn1+adawm on load ----------
__global__ __launch_bounds__(256) void k_attn(
    const float* __restrict__ x0,
    const float* __restrict__ stats, const float* __restrict__ gg, const float* __restrict__ gb,
    const float* __restrict__ sv,
    const float* __restrict__ qkv_w, const float* __restrict__ qkv_b,
    const float* __restrict__ proj_w, const float* __restrict__ proj_b,
    float* __restrict__ x1out, double* __restrict__ gn2_sum, double* __restrict__ gn2_sq)
{
  __shared__ float qkvbuf[16*577];
  __shared__ float xabuf[3200];

  float* xw  = xabuf;          // [c][t] during qkv phase
  float* ao  = xabuf;          // [t][c] pitch 200 afterwards
  float* qkv = qkvbuf;         // [t][o] pitch 577
  float* rs_ = qkvbuf;         // epilogue reduction (qkv dead)
  float* rq_ = qkvbuf + 256;

  int tid = threadIdx.x;
  int blk = xcd_swz();         // keep adjacent windows (shared cache lines) on one XCD
  int b  = blk >> 12;
  int wy = (blk >> 6) & 63;
  int wx = blk & 63;

  float mu = stats[2*b], rstd = stats[2*b+1];
  const float* sb = sv + b*768;

  for (int l = tid; l < DIMC*4; l += 256){
    int c = l >> 2, q = l & 3;
    int qy = q >> 1, qx = q & 1;
    const float* p = x0 + ((size_t)(b*DIMC + c)*NH + (wy*4 + qy*2))*NW + wx*4 + qx*2;
    float2 t0 = *(const float2*)p;
    float2 t1 = *(const float2*)(p + NW);
    float gc = gg[c], bc = gb[c];
    float n00 = (t0.x-mu)*rstd*gc + bc;
    float n01 = (t0.y-mu)*rstd*gc + bc;
    float n10 = (t1.x-mu)*rstd*gc + bc;
    float n11 = (t1.y-mu)*rstd*gc + bc;
    float ll = (n00+n01+n10+n11)*0.5f*sb[c];
    float hl = (n00-n10+n01-n11)*0.5f*sb[192+c];
    float lh = (n00+n10-n01-n11)*0.5f*sb[384+c];
    float hh = (n00-n10-n01+n11)*0.5f*sb[576+c];
    float* d = &xw[c*16 + qy*8 + qx*2];
    d[0] = (ll+hl+lh+hh)*0.5f;
    d[1] = (ll+hl-lh-hh)*0.5f;
    d[4] = (ll-hl+lh-hh)*0.5f;
    d[5] = (ll-hl-lh+hh)*0.5f;
  }
  __syncthreads();

  if (tid < 192){
    float acc[3][16];
    #pragma unroll
    for (int k = 0; k < 3; k++)
      #pragma unroll
      for (int t = 0; t < 16; t++) acc[k][t] = 0.f;
    const float* wp = qkv_w + tid;
    for (int c = 0; c < DIMC; c++){
      float xv[16];
      #pragma unroll
      for (int t = 0; t < 16; t++) xv[t] = xw[c*16 + t];
      #pragma unroll
      for (int k = 0; k < 3; k++){
        float w = wp[c*576 + 192*k];
        #pragma unroll
        for (int t = 0; t < 16; t++) acc[k][t] += xv[t] * w;
      }
    }
    #pragma unroll
    for (int k = 0; k < 3; k++){
      int o = tid + 192*k;
      float bq = qkv_b[o];
      #pragma unroll
      for (int t = 0; t < 16; t++) qkv[t*577 + o] = acc[k][t] + bq;
    }
  }
  __syncthreads();

  if (tid < 96){
    int h = tid >> 4, q = tid & 15;
    float sc[16]; float mx = -1e30f;
    for (int kt = 0; kt < 16; kt++){
      float d = 0.f;
      #pragma unroll
      for (int e = 0; e < HDIM; e++)
        d += qkv[q*577 + h*HDIM + e] * qkv[kt*577 + 192 + h*HDIM + e];
      d *= 0.17677669529663687f;
      sc[kt] = d; mx = fmaxf(mx, d);
    }
    float sum = 0.f;
    for (int kt = 0; kt < 16; kt++){ float e = expf(sc[kt]-mx); sc[kt]=e; sum+=e; }
    float inv = 1.f/sum;
    for (int e = 0; e < HDIM; e++){
      float a = 0.f;
      for (int kt = 0; kt < 16; kt++) a += sc[kt]*qkv[kt*577 + 384 + h*HDIM + e];
      ao[q*200 + h*HDIM + e] = a*inv;
    }
  }
  __syncthreads();

  float lsum = 0.f, lsq = 0.f;
  if (tid < DIMC){
    int o = tid;
    float acc[16];
    float pb = proj_b[o];
    #pragma unroll
    for (int t = 0; t < 16; t++) acc[t] = pb;
    for (int c = 0; c < DIMC; c++){
      float w = proj_w[c*DIMC + o];
      #pragma unroll
      for (int t = 0; t < 16; t++) acc[t] += ao[t*200 + c]*w;
    }
    #pragma unroll
    for (int t4 = 0; t4 < 4; t4++){
      int y = wy*4 + t4;
      size_t addr = ((size_t)(b*DIMC + o)*NH + y)*NW + wx*4;
      float4 xv = *(const float4*)&x0[addr];
      float4 ov;
      ov.x = xv.x + acc[t4*4+0];
      ov.y = xv.y + acc[t4*4+1];
      ov.z = xv.z + acc[t4*4+2];
      ov.w = xv.w + acc[t4*4+3];
      *(float4*)&x1out[addr] = ov;
      lsum += ov.x+ov.y+ov.z+ov.w;
      lsq  += ov.x*ov.x + ov.y*ov.y + ov.z*ov.z + ov.w*ov.w;
    }
  }
  rs_[tid] = lsum; rq_[tid] = lsq;
  __syncthreads();
  for (int st = 128; st > 0; st >>= 1){
    if (tid < st){ rs_[tid] += rs_[tid+st]; rq_[tid] += rq_[tid+st]; }
    __syncthreads();
  }
  if (tid == 0){
    atomicAdd(&gn2_sum[b], (double)rs_[0]);
    atomicAdd(&gn2_sq[b], (double)rq_[0]);
  }
}

// ---------- gdfn stage 1: fused gn2+adawm + pointwise 192->1020 into strip buffer T (bf16)
// runtime strip size: grid = 16*trows*NB (1D, XCD-swizzled)
__global__ __launch_bounds__(256) void k_pin(
    const float* __restrict__ x1, const float* __restrict__ stats,
    const float* __restrict__ gg, const float* __restrict__ gb, const float* __restrict__ sv,
    const float* __restrict__ pin_wT, const float* __restrict__ pin_b,
    u16* __restrict__ T, int s, int strip, int trows)
{
  __shared__ float px[DIMC*16]; // [c][p]
  int tid = threadIdx.x;
  int virt = xcd_swz();
  int xc = virt & 15;
  int rb = virt >> 4;
  int r = rb % trows;
  int b = rb / trows;
  int y = s*strip - 1 + r;
  int x0 = xc*16;
  u16* Trow = T + ((size_t)(b*trows + r)*NW + x0)*HID2C;
  bool valid = (y >= 0) && (y < NH);
  if (!valid){
    for (int l = tid; l < 16*HID2C; l += 256) Trow[l] = 0;
    return;
  }
  float mu = stats[2*b], rstd = stats[2*b+1];
  const float* sb = sv + b*768;
  int ytop = y & ~1;
  bool istop = (y == ytop);
  for (int l = tid; l < DIMC*8; l += 256){
    int c = l >> 3, u = l & 7;
    const float* p = x1 + ((size_t)(b*DIMC + c)*NH + ytop)*NW + x0 + 2*u;
    float2 t0 = *(const float2*)p;
    float2 t1 = *(const float2*)(p + NW);
    float gc = gg[c], bc = gb[c];
    float n00 = (t0.x-mu)*rstd*gc + bc;
    float n01 = (t0.y-mu)*rstd*gc + bc;
    float n10 = (t1.x-mu)*rstd*gc + bc;
    float n11 = (t1.y-mu)*rstd*gc + bc;
    float ll = (n00+n01+n10+n11)*0.5f*sb[c];
    float hl = (n00-n10+n01-n11)*0.5f*sb[192+c];
    float lh = (n00+n10-n01-n11)*0.5f*sb[384+c];
    float hh = (n00-n10-n01+n11)*0.5f*sb[576+c];
    float v0, v1;
    if (istop){ v0 = (ll+hl+lh+hh)*0.5f; v1 = (ll+hl-lh-hh)*0.5f; }
    else      { v0 = (ll-hl+lh-hh)*0.5f; v1 = (ll-hl-lh+hh)*0.5f; }
    px[c*16 + 2*u]     = v0;
    px[c*16 + 2*u + 1] = v1;
  }
  __syncthreads();
  if (tid < 255){
    int o4 = tid*4;
    float4 bi = *(const float4*)&pin_b[o4];
    float acc[16][4];
    #pragma unroll
    for (int p = 0; p < 16; p++){ acc[p][0]=bi.x; acc[p][1]=bi.y; acc[p][2]=bi.z; acc[p][3]=bi.w; }
    for (int c = 0; c < DIMC; c++){
      float4 w = *(const float4*)&pin_wT[(size_t)c*HID2C + o4];
      #pragma unroll
      for (int p = 0; p < 16; p++){
        float xv = px[c*16 + p];
        acc[p][0] += xv*w.x; acc[p][1] += xv*w.y; acc[p][2] += xv*w.z; acc[p][3] += xv*w.w;
      }
    }
    for (int p = 0; p < 16; p++){
      ushort4 o; o.x=f2bf(acc[p][0]); o.y=f2bf(acc[p][1]); o.z=f2bf(acc[p][2]); o.w=f2bf(acc[p][3]);
      *(ushort4*)&Trow[(size_t)p*HID2C + o4] = o;
    }
  }
}

// ---------- gdfn stage 2: depthwise 3x3 + gelu-gate + pointwise 510->192
#define DW_TAPS(XGUARD)                                                          \
  _Pragma("unroll")                                                              \
  for (int dy = 0; dy < 3; dy++){                                                \
    const u16* Tr = Tbase + (size_t)dy*NW*HID2C;                                 \
    _Pragma("unroll")                                                            \
    for (int dx = -1; dx <= 1; dx++){                                            \
      int xx = gx + dx;                                                          \
      XGUARD                                                                     \
      int wi = dy*3 + (dx+1);                                                    \
      const u16* pp = Tr + (size_t)xx*HID2C + c0;                                \
      unsigned int lo = *(const unsigned int*)pp;                                \
      unsigned int hi = *(const unsigned int*)(pp + HIDC);                       \
      a0 += wA[wi]*bf2f((u16)lo);  a1 += wB[wi]*bf2f((u16)(lo>>16));             \
      a2 += wC[wi]*bf2f((u16)hi);  a3 += wD[wi]*bf2f((u16)(hi>>16));             \
    }                                                                            \
  }

__global__ __launch_bounds__(256) void k_dwgate(
    const u16* __restrict__ T, const float* __restrict__ pout_wT,
    const float* __restrict__ dw_w, const float* __restrict__ dw_b,
    const float* __restrict__ pout_b, u16* __restrict__ G,
    float* __restrict__ se_sum, int s, int strip, int trows)
{
  __shared__ float g[16][512];
  int tid = threadIdx.x;
  int virt = xcd_swz();
  int xc = virt & 15;
  int rb = virt >> 4;
  int ry = rb % strip;
  int b = rb / strip;
  int y = s*strip + ry;
  int x0 = xc*16;
  int r = ry + 1;
  if (tid < 255){
    int c0 = 2*tid;
    float wA[9], wB[9], wC[9], wD[9];
    #pragma unroll
    for (int t9 = 0; t9 < 9; t9++){
      wA[t9] = dw_w[c0*9+t9];          wB[t9] = dw_w[(c0+1)*9+t9];
      wC[t9] = dw_w[(c0+HIDC)*9+t9];   wD[t9] = dw_w[(c0+HIDC+1)*9+t9];
    }
    float dbA = dw_b[c0], dbB = dw_b[c0+1], dbC = dw_b[c0+HIDC], dbD = dw_b[c0+HIDC+1];
    const u16* Tbase = T + (size_t)(b*trows + r - 1)*NW*HID2C;
    bool interior = (x0 > 0) && (x0 + 16 < NW);
    if (interior){
      for (int p = 0; p < 16; p++){
        int gx = x0 + p;
        float a0=dbA, a1=dbB, a2=dbC, a3=dbD;
        DW_TAPS()
        float geA = 0.5f*a0*(1.f + erff(a0*0.70710678118654752f));
        float geB = 0.5f*a1*(1.f + erff(a1*0.70710678118654752f));
        g[p][c0]   = geA*a2;
        g[p][c0+1] = geB*a3;
      }
    } else {
      for (int p = 0; p < 16; p++){
        int gx = x0 + p;
        float a0=dbA, a1=dbB, a2=dbC, a3=dbD;
        DW_TAPS(if (xx < 0 || xx >= NW) continue;)
        float geA = 0.5f*a0*(1.f + erff(a0*0.70710678118654752f));
        float geB = 0.5f*a1*(1.f + erff(a1*0.70710678118654752f));
        g[p][c0]   = geA*a2;
        g[p][c0+1] = geB*a3;
      }
    }
  }
  __syncthreads();
  if (tid < DIMC){
    int o = tid;
    float pb = pout_b[o];
    float acc[16];
    #pragma unroll
    for (int p = 0; p < 16; p++) acc[p] = pb;
    for (int c = 0; c < HIDC; c++){
      float w = pout_wT[(size_t)c*DIMC + o];
      #pragma unroll
      for (int p = 0; p < 16; p++) acc[p] += g[p][c]*w;
    }
    float lsum = 0.f;
    u16* Gp = G + ((size_t)(b*DIMC + o)*NH + y)*NW + x0;
    #pragma unroll
    for (int q4 = 0; q4 < 4; q4++){
      ushort4 ov;
      ov.x = f2bf(acc[q4*4+0]); ov.y = f2bf(acc[q4*4+1]);
      ov.z = f2bf(acc[q4*4+2]); ov.w = f2bf(acc[q4*4+3]);
      *(ushort4*)&Gp[q4*4] = ov;
    }
    #pragma unroll
    for (int p = 0; p < 16; p++) lsum += acc[p];
    atomicAdd(&se_sum[b*DIMC + o], lsum);  // native fp32 atomic (no CAS loop)
  }
}

// ---------- SE gate vector ----------
__global__ __launch_bounds__(256) void k_se(const float* __restrict__ se_sum,
    const float* __restrict__ w1, const float* __restrict__ w2, float* __restrict__ sey)
{
  __shared__ float mean[NB*DIMC];
  __shared__ float hid[NB*REDC];
  int tid = threadIdx.x;
  for (int i = tid; i < NB*DIMC; i += 256) mean[i] = se_sum[i] * (1.f/(float)HW);
  __syncthreads();
  for (int i = tid; i < NB*REDC; i += 256){
    int b = i / REDC, rr = i % REDC;
    float a = 0.f;
    for (int c = 0; c < DIMC; c++) a += mean[b*DIMC + c]*w1[c*REDC + rr];
    hid[i] = fmaxf(a, 0.f);
  }
  __syncthreads();
  for (int i = tid; i < NB*DIMC; i += 256){
    int b = i / DIMC, o = i % DIMC;
    float a = 0.f;
    for (int rr = 0; rr < REDC; rr++) a += hid[b*REDC + rr]*w2[rr*DIMC + o];
    sey[i] = 1.f/(1.f + expf(-a));
  }
}

// ---------- final: out = x1 + G * sey ----------
__global__ __launch_bounds__(256) void k_final(const u16* __restrict__ G,
    const float* __restrict__ sey, float* __restrict__ xout)
{
  int i4 = blockIdx.x*256 + threadIdx.x;
  int cpix = i4 >> 14;              // b*DIMC + c
  float sc = sey[cpix];
  ushort4 gv = *(const ushort4*)&G[(size_t)i4*4];
  float4 xv = *(const float4*)&xout[(size_t)i4*4];
  float4 ov;
  ov.x = xv.x + bf2f(gv.x)*sc;
  ov.y = xv.y + bf2f(gv.y)*sc;
  ov.z = xv.z + bf2f(gv.z)*sc;
  ov.w = xv.w + bf2f(gv.w)*sc;
  *(float4*)&xout[(size_t)i4*4] = ov;
}

extern "C" void kernel_launch(void* const* d_in, const int* in_sizes, int n_in,
                              void* d_out, int out_size, void* d_ws, size_t ws_size,
                              hipStream_t stream)
{
  const float* x      = (const float*)d_in[0];
  const float* temb   = (const float*)d_in[1];
  const float* gn1_g  = (const float*)d_in[2];
  const float* gn1_b  = (const float*)d_in[3];
  const float* aw1_w1 = (const float*)d_in[4];
  const float* aw1_b1 = (const float*)d_in[5];
  const float* aw1_w2 = (const float*)d_in[6];
  const float* aw1_b2 = (const float*)d_in[7];
  const float* qkv_w  = (const float*)d_in[8];
  const float* qkv_b  = (const float*)d_in[9];
  const float* proj_w = (const float*)d_in[10];
  const float* proj_b = (const float*)d_in[11];
  const float* gn2_g  = (const float*)d_in[12];
  const float* gn2_b  = (const float*)d_in[13];
  const float* aw2_w1 = (const float*)d_in[14];
  const float* aw2_b1 = (const float*)d_in[15];
  const float* aw2_w2 = (const float*)d_in[16];
  const float* aw2_b2 = (const float*)d_in[17];
  const float* pin_w  = (const float*)d_in[18];
  const float* pin_b  = (const float*)d_in[19];
  const float* dw_w   = (const float*)d_in[20];
  const float* dw_b   = (const float*)d_in[21];
  const float* pout_w = (const float*)d_in[22];
  const float* pout_b = (const float*)d_in[23];
  const float* se_w1  = (const float*)d_in[24];
  const float* se_w2  = (const float*)d_in[25];

  unsigned char* ws = (unsigned char*)d_ws;
  // scalars/atomics block (zeroed each launch)
  double* gn1_sum = (double*)ws;                 // 4
  double* gn1_sq  = gn1_sum + 4;
  double* gn2_sum = gn1_sum + 8;
  double* gn2_sq  = gn1_sum + 12;                // 16 doubles
  float*  se_sumf = (float*)(ws + 128);          // 768 floats -> ends at 3200
  float*  fbase   = (float*)(ws + 3200);
  float* s1      = fbase;                        // 3072
  float* s2      = s1 + 3072;                    // 3072
  float* stats1  = s2 + 3072;                    // 8
  float* stats2  = stats1 + 8;                   // 8
  float* sey     = stats2 + 8;                   // 768
  float* pin_wT  = sey + 768;                    // 192*1020
  float* pout_wT = pin_wT + (size_t)HID2C*DIMC;  // 510*192
  size_t offG = ((3200 + (size_t)300688*4) + 255) & ~(size_t)255;
  u16* G  = (u16*)(ws + offG);                   // 100.7 MB
  size_t offT = offG + (size_t)NB*DIMC*HW*2;
  u16* Tb = (u16*)(ws + offT);

  // pick largest strip that fits the workspace
  int S = 64;
  if (ws_size < offT + (size_t)NB*(64+2)*NW*HID2C*2) S = 32;
  if (S == 32 && ws_size < offT + (size_t)NB*(32+2)*NW*HID2C*2) S = 16;
  int trows = S + 2;
  int nstrips = NH / S;

  float* x1 = (float*)d_out;

  hipMemsetAsync(ws, 0, 3200, stream);
  k_prep<<<765, 256, 0, stream>>>(pin_w, pout_w, pin_wT, pout_wT);
  k_reduce<<<dim3(1024,4), 256, 0, stream>>>(x, gn1_sum, gn1_sq);
  k_stats<<<1, 64, 0, stream>>>(gn1_sum, gn1_sq, stats1);
  k_svec<<<1, 256, 0, stream>>>(temb, aw1_w1, aw1_b1, aw1_w2, aw1_b2, s1);
  k_svec<<<1, 256, 0, stream>>>(temb, aw2_w1, aw2_b1, aw2_w2, aw2_b2, s2);
  k_attn<<<16384, 256, 0, stream>>>(x, stats1, gn1_g, gn1_b, s1,
                                    qkv_w, qkv_b, proj_w, proj_b, x1, gn2_sum, gn2_sq);
  k_stats<<<1, 64, 0, stream>>>(gn2_sum, gn2_sq, stats2);
  for (int s = 0; s < nstrips; s++){
    k_pin<<<16*trows*NB, 256, 0, stream>>>(x1, stats2, gn2_g, gn2_b, s2,
                                           pin_wT, pin_b, Tb, s, S, trows);
    k_dwgate<<<16*S*NB, 256, 0, stream>>>(Tb, pout_wT, dw_w, dw_b, pout_b, G, se_sumf, s, S, trows);
  }
  k_se<<<1, 256, 0, stream>>>(se_sumf, se_w1, se_w2, sey);
  k_final<<<49152, 256, 0, stream>>>(G, sey, x1);
}

// Round 3
// 3461.603 us; speedup vs baseline: 8.7150x; 1.4925x over previous
//
#include <hip/hip_runtime.h>
#include <hip/hip_bf16.h>
#include <cmath>

#define DIMC 192
#define NHEAD 6
#define HDIM 32
#define TDIM 128
#define HIDC 510
#define HID2C 1020
#define REDC 24
#define NB 4
#define NH 256
#define NW 256
#define HW 65536
#define NPB (DIMC*HW)

typedef unsigned short u16;
typedef unsigned int u32;
typedef short bf16x8 __attribute__((ext_vector_type(8)));
typedef float f32x4 __attribute__((ext_vector_type(4)));

__device__ __forceinline__ float bf2f(u16 u){
  union { unsigned int i; float f; } v; v.i = ((unsigned int)u) << 16; return v.f;
}
__device__ __forceinline__ u16 f2bf(float f){
  union { float f; unsigned int i; } v; v.f = f;
  unsigned int i = v.i;
  return (u16)((i + 0x7FFFu + ((i >> 16) & 1u)) >> 16);
}
// XCD-chunked bijective swizzle (requires gridDim.x % 8 == 0)
__device__ __forceinline__ int xcd_swz(){
  int n = gridDim.x, l = blockIdx.x;
  return (l & 7)*(n >> 3) + (l >> 3);
}

// ---------- pack pin_w / pout_w into MFMA B-fragment layout (bf16) ----------
// wpk1: [ks=0..5][cq=0..3][o=0..1023][j=0..7]  (c = ks*32+cq*8+j, pin: out 1020->pad 1024)
// wpk2: [ks=0..15][cq=0..3][o=0..191][j=0..7]  (c = ks*32+cq*8+j over 512 (510 padded))
__global__ __launch_bounds__(256) void k_prep(const float* __restrict__ pin_w,
    const float* __restrict__ pout_w, u16* __restrict__ wpk1, u16* __restrict__ wpk2)
{
  int i = blockIdx.x*256 + threadIdx.x;
  if (i < 6*4*1024*8){
    int j = i & 7, o = (i >> 3) & 1023, kscq = i >> 13;
    int c = kscq*8 + j;
    wpk1[i] = (o < HID2C) ? f2bf(pin_w[o*DIMC + c]) : (u16)0;
  }
  if (i < 16*4*192*8){
    int j = i & 7, o = (i >> 3) % 192, kscq = (i >> 3) / 192;
    int c = kscq*8 + j;
    wpk2[i] = (c < HIDC) ? f2bf(pout_w[o*HIDC + c]) : (u16)0;
  }
}

// ---------- per-batch sum/sumsq over x ----------
__global__ __launch_bounds__(256) void k_reduce(const float* __restrict__ x,
    double* __restrict__ sum, double* __restrict__ sq)
{
  int b = blockIdx.y;
  const float4* xb = (const float4*)(x + (size_t)b*NPB);
  float ls = 0.f, lq = 0.f;
  int n4 = NPB/4;
  for (int i = blockIdx.x*256 + threadIdx.x; i < n4; i += gridDim.x*256){
    float4 u = xb[i];
    ls += u.x+u.y+u.z+u.w; lq += u.x*u.x + u.y*u.y + u.z*u.z + u.w*u.w;
  }
  __shared__ float rs_[256], rq_[256];
  int tid = threadIdx.x;
  rs_[tid]=ls; rq_[tid]=lq; __syncthreads();
  for (int st=128; st>0; st>>=1){ if (tid<st){ rs_[tid]+=rs_[tid+st]; rq_[tid]+=rq_[tid+st]; } __syncthreads(); }
  if (tid==0){ atomicAdd(&sum[b], (double)rs_[0]); atomicAdd(&sq[b], (double)rq_[0]); }
}

__global__ void k_stats(const double* __restrict__ sum, const double* __restrict__ sq,
                        float* __restrict__ stats)
{
  int t = threadIdx.x;
  if (t < NB){
    double mu = sum[t] / (double)NPB;
    double var = sq[t] / (double)NPB - mu*mu;
    stats[2*t]   = (float)mu;
    stats[2*t+1] = (float)(1.0 / sqrt(var + 1e-5));
  }
}

// ---------- s = silu(temb@w1+b1)@w2+b2 ----------
__global__ __launch_bounds__(256) void k_svec(const float* __restrict__ temb,
    const float* __restrict__ w1, const float* __restrict__ b1,
    const float* __restrict__ w2, const float* __restrict__ b2, float* __restrict__ s)
{
  __shared__ float te[NB*TDIM];
  __shared__ float hid[NB*TDIM];
  int tid = threadIdx.x;
  for (int i = tid; i < NB*TDIM; i += 256) te[i] = temb[i];
  __syncthreads();
  for (int i = tid; i < NB*TDIM; i += 256){
    int b = i >> 7, j = i & 127;
    float a = b1[j];
    for (int c = 0; c < TDIM; c++) a += te[b*TDIM + c]*w1[c*TDIM + j];
    hid[i] = a / (1.f + expf(-a));
  }
  __syncthreads();
  for (int i = tid; i < NB*4*DIMC; i += 256){
    int b = i / 768, o = i % 768;
    float a = b2[o];
    for (int c = 0; c < TDIM; c++) a += hid[b*TDIM + c]*w2[c*768 + o];
    s[i] = a;
  }
}

// ---------- window attention with fused gn1+adawm on load ----------
__global__ __launch_bounds__(256) void k_attn(
    const float* __restrict__ x0,
    const float* __restrict__ stats, const float* __restrict__ gg, const float* __restrict__ gb,
    const float* __restrict__ sv,
    const float* __restrict__ qkv_w, const float* __restrict__ qkv_b,
    const float* __restrict__ proj_w, const float* __restrict__ proj_b,
    float* __restrict__ x1out, double* __restrict__ gn2_sum, double* __restrict__ gn2_sq)
{
  __shared__ float qkvbuf[16*577];
  __shared__ float xabuf[3200];

  float* xw  = xabuf;          // [c][t] during qkv phase
  float* ao  = xabuf;          // [t][c] pitch 200 afterwards
  float* qkv = qkvbuf;         // [t][o] pitch 577
  float* rs_ = qkvbuf;         // epilogue reduction (qkv dead)
  float* rq_ = qkvbuf + 256;

  int tid = threadIdx.x;
  int blk = xcd_swz();         // keep adjacent windows (shared cache lines) on one XCD
  int b  = blk >> 12;
  int wy = (blk >> 6) & 63;
  int wx = blk & 63;

  float mu = stats[2*b], rstd = stats[2*b+1];
  const float* sb = sv + b*768;

  for (int l = tid; l < DIMC*4; l += 256){
    int c = l >> 2, q = l & 3;
    int qy = q >> 1, qx = q & 1;
    const float* p = x0 + ((size_t)(b*DIMC + c)*NH + (wy*4 + qy*2))*NW + wx*4 + qx*2;
    float2 t0 = *(const float2*)p;
    float2 t1 = *(const float2*)(p + NW);
    float gc = gg[c], bc = gb[c];
    float n00 = (t0.x-mu)*rstd*gc + bc;
    float n01 = (t0.y-mu)*rstd*gc + bc;
    float n10 = (t1.x-mu)*rstd*gc + bc;
    float n11 = (t1.y-mu)*rstd*gc + bc;
    float ll = (n00+n01+n10+n11)*0.5f*sb[c];
    float hl = (n00-n10+n01-n11)*0.5f*sb[192+c];
    float lh = (n00+n10-n01-n11)*0.5f*sb[384+c];
    float hh = (n00-n10-n01+n11)*0.5f*sb[576+c];
    float* d = &xw[c*16 + qy*8 + qx*2];
    d[0] = (ll+hl+lh+hh)*0.5f;
    d[1] = (ll+hl-lh-hh)*0.5f;
    d[4] = (ll-hl+lh-hh)*0.5f;
    d[5] = (ll-hl-lh+hh)*0.5f;
  }
  __syncthreads();

  if (tid < 192){
    float acc[3][16];
    #pragma unroll
    for (int k = 0; k < 3; k++)
      #pragma unroll
      for (int t = 0; t < 16; t++) acc[k][t] = 0.f;
    const float* wp = qkv_w + tid;
    for (int c = 0; c < DIMC; c++){
      float xv[16];
      #pragma unroll
      for (int t = 0; t < 16; t++) xv[t] = xw[c*16 + t];
      #pragma unroll
      for (int k = 0; k < 3; k++){
        float w = wp[c*576 + 192*k];
        #pragma unroll
        for (int t = 0; t < 16; t++) acc[k][t] += xv[t] * w;
      }
    }
    #pragma unroll
    for (int k = 0; k < 3; k++){
      int o = tid + 192*k;
      float bq = qkv_b[o];
      #pragma unroll
      for (int t = 0; t < 16; t++) qkv[t*577 + o] = acc[k][t] + bq;
    }
  }
  __syncthreads();

  if (tid < 96){
    int h = tid >> 4, q = tid & 15;
    float sc[16]; float mx = -1e30f;
    for (int kt = 0; kt < 16; kt++){
      float d = 0.f;
      #pragma unroll
      for (int e = 0; e < HDIM; e++)
        d += qkv[q*577 + h*HDIM + e] * qkv[kt*577 + 192 + h*HDIM + e];
      d *= 0.17677669529663687f;
      sc[kt] = d; mx = fmaxf(mx, d);
    }
    float sum = 0.f;
    for (int kt = 0; kt < 16; kt++){ float e = expf(sc[kt]-mx); sc[kt]=e; sum+=e; }
    float inv = 1.f/sum;
    for (int e = 0; e < HDIM; e++){
      float a = 0.f;
      for (int kt = 0; kt < 16; kt++) a += sc[kt]*qkv[kt*577 + 384 + h*HDIM + e];
      ao[q*200 + h*HDIM + e] = a*inv;
    }
  }
  __syncthreads();

  float lsum = 0.f, lsq = 0.f;
  if (tid < DIMC){
    int o = tid;
    float acc[16];
    float pb = proj_b[o];
    #pragma unroll
    for (int t = 0; t < 16; t++) acc[t] = pb;
    for (int c = 0; c < DIMC; c++){
      float w = proj_w[c*DIMC + o];
      #pragma unroll
      for (int t = 0; t < 16; t++) acc[t] += ao[t*200 + c]*w;
    }
    #pragma unroll
    for (int t4 = 0; t4 < 4; t4++){
      int y = wy*4 + t4;
      size_t addr = ((size_t)(b*DIMC + o)*NH + y)*NW + wx*4;
      float4 xv = *(const float4*)&x0[addr];
      float4 ov;
      ov.x = xv.x + acc[t4*4+0];
      ov.y = xv.y + acc[t4*4+1];
      ov.z = xv.z + acc[t4*4+2];
      ov.w = xv.w + acc[t4*4+3];
      *(float4*)&x1out[addr] = ov;
      lsum += ov.x+ov.y+ov.z+ov.w;
      lsq  += ov.x*ov.x + ov.y*ov.y + ov.z*ov.z + ov.w*ov.w;
    }
  }
  rs_[tid] = lsum; rq_[tid] = lsq;
  __syncthreads();
  for (int st = 128; st > 0; st >>= 1){
    if (tid < st){ rs_[tid] += rs_[tid+st]; rq_[tid] += rq_[tid+st]; }
    __syncthreads();
  }
  if (tid == 0){
    atomicAdd(&gn2_sum[b], (double)rs_[0]);
    atomicAdd(&gn2_sq[b], (double)rq_[0]);
  }
}

// ---------- gdfn stage 1: fused gn2+adawm + MFMA pointwise 192->1020 into strip T (bf16)
// A-frag LDS layout: pxb[(c>>3)*16 + p][j=c&7]  (bf16, 16B-aligned octets)
__global__ __launch_bounds__(256) void k_pin(
    const float* __restrict__ x1, const float* __restrict__ stats,
    const float* __restrict__ gg, const float* __restrict__ gb, const float* __restrict__ sv,
    const u16* __restrict__ wpk1, const float* __restrict__ pin_b,
    u16* __restrict__ T, int s, int strip, int trows)
{
  __shared__ __align__(16) u16 pxb[24*16*8];   // 6 KB
  int tid = threadIdx.x;
  int virt = xcd_swz();
  int xc = virt & 15;
  int rb = virt >> 4;
  int r = rb % trows;
  int b = rb / trows;
  int y = s*strip - 1 + r;
  int x0 = xc*16;
  u16* Trow = T + ((size_t)(b*trows + r)*NW + x0)*HID2C;
  bool valid = (y >= 0) && (y < NH);
  if (!valid){
    for (int l = tid; l < 16*HID2C; l += 256) Trow[l] = 0;
    return;
  }
  float mu = stats[2*b], rstd = stats[2*b+1];
  const float* sb = sv + b*768;
  int ytop = y & ~1;
  bool istop = (y == ytop);
  for (int l = tid; l < DIMC*8; l += 256){
    int c = l >> 3, u = l & 7;
    const float* p = x1 + ((size_t)(b*DIMC + c)*NH + ytop)*NW + x0 + 2*u;
    float2 t0 = *(const float2*)p;
    float2 t1 = *(const float2*)(p + NW);
    float gc = gg[c], bc = gb[c];
    float n00 = (t0.x-mu)*rstd*gc + bc;
    float n01 = (t0.y-mu)*rstd*gc + bc;
    float n10 = (t1.x-mu)*rstd*gc + bc;
    float n11 = (t1.y-mu)*rstd*gc + bc;
    float ll = (n00+n01+n10+n11)*0.5f*sb[c];
    float hl = (n00-n10+n01-n11)*0.5f*sb[192+c];
    float lh = (n00+n10-n01-n11)*0.5f*sb[384+c];
    float hh = (n00-n10-n01+n11)*0.5f*sb[576+c];
    float v0, v1;
    if (istop){ v0 = (ll+hl+lh+hh)*0.5f; v1 = (ll+hl-lh-hh)*0.5f; }
    else      { v0 = (ll-hl+lh-hh)*0.5f; v1 = (ll-hl-lh+hh)*0.5f; }
    int cq = c >> 3, j = c & 7;
    pxb[((cq*16 + 2*u)*8) + j]     = f2bf(v0);
    pxb[((cq*16 + 2*u + 1)*8) + j] = f2bf(v1);
  }
  __syncthreads();

  int wv = tid >> 6, lane = tid & 63;
  int colo = lane & 15, rowg = lane >> 4;
  const bf16x8* pxv = (const bf16x8*)pxb;
  const bf16x8* wv1 = (const bf16x8*)wpk1;
  bf16x8 a6[6];
  #pragma unroll
  for (int ks = 0; ks < 6; ks++)
    a6[ks] = pxv[(ks*4 + rowg)*16 + colo];
  for (int nt16 = 0; nt16 < 16; nt16++){
    int nt = wv*16 + nt16;
    f32x4 acc = {0.f, 0.f, 0.f, 0.f};
    #pragma unroll
    for (int ks = 0; ks < 6; ks++)
      acc = __builtin_amdgcn_mfma_f32_16x16x32_bf16(a6[ks],
              wv1[(ks*4 + rowg)*1024 + nt*16 + colo], acc, 0, 0, 0);
    int o = nt*16 + colo;
    if (o < HID2C){
      float pb = pin_b[o];
      #pragma unroll
      for (int i = 0; i < 4; i++)
        Trow[(size_t)(rowg*4 + i)*HID2C + o] = f2bf(acc[i] + pb);
    }
  }
}

// ---------- gdfn stage 2: depthwise 3x3 + gelu-gate (scalar) + MFMA pout 512->192
#define DW_TAPS(XGUARD)                                                          \
  _Pragma("unroll")                                                              \
  for (int dy = 0; dy < 3; dy++){                                                \
    const u16* Tr = Tbase + (size_t)dy*NW*HID2C;                                 \
    _Pragma("unroll")                                                            \
    for (int dx = -1; dx <= 1; dx++){                                            \
      int xx = gx + dx;                                                          \
      XGUARD                                                                     \
      int wi = dy*3 + (dx+1);                                                    \
      const u16* pp = Tr + (size_t)xx*HID2C + c0;                                \
      unsigned int lo = *(const unsigned int*)pp;                                \
      unsigned int hi = *(const unsigned int*)(pp + HIDC);                       \
      a0 += wA[wi]*bf2f((u16)lo);  a1 += wB[wi]*bf2f((u16)(lo>>16));             \
      a2 += wC[wi]*bf2f((u16)hi);  a3 += wD[wi]*bf2f((u16)(hi>>16));             \
    }                                                                            \
  }

__global__ __launch_bounds__(256) void k_dwgate(
    const u16* __restrict__ T, const u16* __restrict__ wpk2,
    const float* __restrict__ dw_w, const float* __restrict__ dw_b,
    const float* __restrict__ pout_b, u16* __restrict__ G,
    float* __restrict__ se_sum, int s, int strip, int trows)
{
  __shared__ __align__(16) u16 gbuf[16*512];   // 16 KB, A-frag friendly [p][c]
  int tid = threadIdx.x;
  int virt = xcd_swz();
  int xc = virt & 15;
  int rb = virt >> 4;
  int ry = rb % strip;
  int b = rb / strip;
  int y = s*strip + ry;
  int x0 = xc*16;
  int r = ry + 1;
  if (tid < 255){
    int c0 = 2*tid;
    float wA[9], wB[9], wC[9], wD[9];
    #pragma unroll
    for (int t9 = 0; t9 < 9; t9++){
      wA[t9] = dw_w[c0*9+t9];          wB[t9] = dw_w[(c0+1)*9+t9];
      wC[t9] = dw_w[(c0+HIDC)*9+t9];   wD[t9] = dw_w[(c0+HIDC+1)*9+t9];
    }
    float dbA = dw_b[c0], dbB = dw_b[c0+1], dbC = dw_b[c0+HIDC], dbD = dw_b[c0+HIDC+1];
    const u16* Tbase = T + (size_t)(b*trows + r - 1)*NW*HID2C;
    bool interior = (x0 > 0) && (x0 + 16 < NW);
    if (interior){
      for (int p = 0; p < 16; p++){
        int gx = x0 + p;
        float a0=dbA, a1=dbB, a2=dbC, a3=dbD;
        DW_TAPS()
        float geA = 0.5f*a0*(1.f + erff(a0*0.70710678118654752f));
        float geB = 0.5f*a1*(1.f + erff(a1*0.70710678118654752f));
        u32 pk = (u32)f2bf(geA*a2) | ((u32)f2bf(geB*a3) << 16);
        *(u32*)&gbuf[p*512 + c0] = pk;
      }
    } else {
      for (int p = 0; p < 16; p++){
        int gx = x0 + p;
        float a0=dbA, a1=dbB, a2=dbC, a3=dbD;
        DW_TAPS(if (xx < 0 || xx >= NW) continue;)
        float geA = 0.5f*a0*(1.f + erff(a0*0.70710678118654752f));
        float geB = 0.5f*a1*(1.f + erff(a1*0.70710678118654752f));
        u32 pk = (u32)f2bf(geA*a2) | ((u32)f2bf(geB*a3) << 16);
        *(u32*)&gbuf[p*512 + c0] = pk;
      }
    }
  } else {
    // zero pad channels 510,511
    for (int p = 0; p < 16; p++) *(u32*)&gbuf[p*512 + 510] = 0;
  }
  __syncthreads();

  int wv = tid >> 6, lane = tid & 63;
  int colo = lane & 15, rowg = lane >> 4;
  const bf16x8* gv = (const bf16x8*)gbuf;
  const bf16x8* wv2 = (const bf16x8*)wpk2;
  f32x4 acc0 = {0.f,0.f,0.f,0.f}, acc1 = {0.f,0.f,0.f,0.f}, acc2 = {0.f,0.f,0.f,0.f};
  int nt0 = wv*3;
  for (int ks = 0; ks < 16; ks++){
    bf16x8 a = gv[colo*64 + ks*4 + rowg];
    const bf16x8* wb = &wv2[(ks*4 + rowg)*192 + colo];
    acc0 = __builtin_amdgcn_mfma_f32_16x16x32_bf16(a, wb[nt0*16],       acc0, 0,0,0);
    acc1 = __builtin_amdgcn_mfma_f32_16x16x32_bf16(a, wb[(nt0+1)*16],   acc1, 0,0,0);
    acc2 = __builtin_amdgcn_mfma_f32_16x16x32_bf16(a, wb[(nt0+2)*16],   acc2, 0,0,0);
  }
  #pragma unroll
  for (int n3 = 0; n3 < 3; n3++){
    f32x4 acc = (n3==0) ? acc0 : (n3==1) ? acc1 : acc2;
    int o = (nt0 + n3)*16 + colo;
    float pb = pout_b[o];
    float v0 = acc[0]+pb, v1 = acc[1]+pb, v2 = acc[2]+pb, v3 = acc[3]+pb;
    ushort4 ov; ov.x = f2bf(v0); ov.y = f2bf(v1); ov.z = f2bf(v2); ov.w = f2bf(v3);
    u16* Gp = G + ((size_t)(b*DIMC + o)*NH + y)*NW + x0 + rowg*4;
    *(ushort4*)Gp = ov;
    float part = v0+v1+v2+v3;
    part += __shfl_xor(part, 16);
    part += __shfl_xor(part, 32);
    if (rowg == 0) atomicAdd(&se_sum[b*DIMC + o], part);
  }
}

// ---------- SE gate vector ----------
__global__ __launch_bounds__(256) void k_se(const float* __restrict__ se_sum,
    const float* __restrict__ w1, const float* __restrict__ w2, float* __restrict__ sey)
{
  __shared__ float mean[NB*DIMC];
  __shared__ float hid[NB*REDC];
  int tid = threadIdx.x;
  for (int i = tid; i < NB*DIMC; i += 256) mean[i] = se_sum[i] * (1.f/(float)HW);
  __syncthreads();
  for (int i = tid; i < NB*REDC; i += 256){
    int b = i / REDC, rr = i % REDC;
    float a = 0.f;
    for (int c = 0; c < DIMC; c++) a += mean[b*DIMC + c]*w1[c*REDC + rr];
    hid[i] = fmaxf(a, 0.f);
  }
  __syncthreads();
  for (int i = tid; i < NB*DIMC; i += 256){
    int b = i / DIMC, o = i % DIMC;
    float a = 0.f;
    for (int rr = 0; rr < REDC; rr++) a += hid[b*REDC + rr]*w2[rr*DIMC + o];
    sey[i] = 1.f/(1.f + expf(-a));
  }
}

// ---------- final: out = x1 + G * sey ----------
__global__ __launch_bounds__(256) void k_final(const u16* __restrict__ G,
    const float* __restrict__ sey, float* __restrict__ xout)
{
  int i4 = blockIdx.x*256 + threadIdx.x;
  int cpix = i4 >> 14;              // b*DIMC + c
  float sc = sey[cpix];
  ushort4 gv = *(const ushort4*)&G[(size_t)i4*4];
  float4 xv = *(const float4*)&xout[(size_t)i4*4];
  float4 ov;
  ov.x = xv.x + bf2f(gv.x)*sc;
  ov.y = xv.y + bf2f(gv.y)*sc;
  ov.z = xv.z + bf2f(gv.z)*sc;
  ov.w = xv.w + bf2f(gv.w)*sc;
  *(float4*)&xout[(size_t)i4*4] = ov;
}

extern "C" void kernel_launch(void* const* d_in, const int* in_sizes, int n_in,
                              void* d_out, int out_size, void* d_ws, size_t ws_size,
                              hipStream_t stream)
{
  const float* x      = (const float*)d_in[0];
  const float* temb   = (const float*)d_in[1];
  const float* gn1_g  = (const float*)d_in[2];
  const float* gn1_b  = (const float*)d_in[3];
  const float* aw1_w1 = (const float*)d_in[4];
  const float* aw1_b1 = (const float*)d_in[5];
  const float* aw1_w2 = (const float*)d_in[6];
  const float* aw1_b2 = (const float*)d_in[7];
  const float* qkv_w  = (const float*)d_in[8];
  const float* qkv_b  = (const float*)d_in[9];
  const float* proj_w = (const float*)d_in[10];
  const float* proj_b = (const float*)d_in[11];
  const float* gn2_g  = (const float*)d_in[12];
  const float* gn2_b  = (const float*)d_in[13];
  const float* aw2_w1 = (const float*)d_in[14];
  const float* aw2_b1 = (const float*)d_in[15];
  const float* aw2_w2 = (const float*)d_in[16];
  const float* aw2_b2 = (const float*)d_in[17];
  const float* pin_w  = (const float*)d_in[18];
  const float* pin_b  = (const float*)d_in[19];
  const float* dw_w   = (const float*)d_in[20];
  const float* dw_b   = (const float*)d_in[21];
  const float* pout_w = (const float*)d_in[22];
  const float* pout_b = (const float*)d_in[23];
  const float* se_w1  = (const float*)d_in[24];
  const float* se_w2  = (const float*)d_in[25];

  unsigned char* ws = (unsigned char*)d_ws;
  // scalars/atomics block (zeroed each launch): 16 doubles + 768 floats = 3200 B
  double* gn1_sum = (double*)ws;
  double* gn1_sq  = gn1_sum + 4;
  double* gn2_sum = gn1_sum + 8;
  double* gn2_sq  = gn1_sum + 12;
  float*  se_sumf = (float*)(ws + 128);
  float*  fbase   = (float*)(ws + 3200);
  float* s1      = fbase;                        // 3072
  float* s2      = s1 + 3072;                    // 3072
  float* stats1  = s2 + 3072;                    // 8
  float* stats2  = stats1 + 8;                   // 8
  float* sey     = stats2 + 8;                   // 768 -> floats end at 30912
  u16* wpk1 = (u16*)(ws + 30976);                // 196608 u16 = 384 KB
  u16* wpk2 = (u16*)(ws + 30976 + 393216);       // 98304 u16 = 192 KB
  size_t offG = 620800;                          // 256-aligned
  u16* G  = (u16*)(ws + offG);                   // 100.7 MB
  size_t offT = offG + (size_t)NB*DIMC*HW*2;
  u16* Tb = (u16*)(ws + offT);

  // pick largest strip that fits the workspace
  int S = 256;
  while (S > 16 && ws_size < offT + (size_t)NB*(S+2)*NW*HID2C*2) S >>= 1;
  int trows = S + 2;
  int nstrips = NH / S;

  float* x1 = (float*)d_out;

  hipMemsetAsync(ws, 0, 3200, stream);
  k_prep<<<768, 256, 0, stream>>>(pin_w, pout_w, wpk1, wpk2);
  k_reduce<<<dim3(1024,4), 256, 0, stream>>>(x, gn1_sum, gn1_sq);
  k_stats<<<1, 64, 0, stream>>>(gn1_sum, gn1_sq, stats1);
  k_svec<<<1, 256, 0, stream>>>(temb, aw1_w1, aw1_b1, aw1_w2, aw1_b2, s1);
  k_svec<<<1, 256, 0, stream>>>(temb, aw2_w1, aw2_b1, aw2_w2, aw2_b2, s2);
  k_attn<<<16384, 256, 0, stream>>>(x, stats1, gn1_g, gn1_b, s1,
                                    qkv_w, qkv_b, proj_w, proj_b, x1, gn2_sum, gn2_sq);
  k_stats<<<1, 64, 0, stream>>>(gn2_sum, gn2_sq, stats2);
  for (int s = 0; s < nstrips; s++){
    k_pin<<<16*trows*NB, 256, 0, stream>>>(x1, stats2, gn2_g, gn2_b, s2,
                                           wpk1, pin_b, Tb, s, S, trows);
    k_dwgate<<<16*S*NB, 256, 0, stream>>>(Tb, wpk2, dw_w, dw_b, pout_b, G, se_sumf, s, S, trows);
  }
  k_se<<<1, 256, 0, stream>>>(se_sumf, se_w1, se_w2, sey);
  k_final<<<49152, 256, 0, stream>>>(G, sey, x1);
}

// Round 4
// 2515.691 us; speedup vs baseline: 11.9918x; 1.3760x over previous
//
#include <hip/hip_runtime.h>
#include <hip/hip_bf16.h>
#include <cmath>

#define DIMC 192
#define NHEAD 6
#define HDIM 32
#define TDIM 128
#define HIDC 510
#define HID2C 1020
#define REDC 24
#define NB 4
#define NH 256
#define NW 256
#define HW 65536
#define NPB (DIMC*HW)

typedef unsigned short u16;
typedef unsigned int u32;
typedef short bf16x8 __attribute__((ext_vector_type(8)));
typedef float f32x4 __attribute__((ext_vector_type(4)));

__device__ __forceinline__ float bf2f(u16 u){
  union { unsigned int i; float f; } v; v.i = ((unsigned int)u) << 16; return v.f;
}
__device__ __forceinline__ u16 f2bf(float f){
  union { float f; unsigned int i; } v; v.f = f;
  unsigned int i = v.i;
  return (u16)((i + 0x7FFFu + ((i >> 16) & 1u)) >> 16);
}
// XCD-chunked bijective swizzle (requires gridDim.x % 8 == 0)
__device__ __forceinline__ int xcd_swz(){
  int n = gridDim.x, l = blockIdx.x;
  return (l & 7)*(n >> 3) + (l >> 3);
}

// ---------- pack pin_w / pout_w / qkv_w / proj_w into MFMA B-fragment bf16 layouts ----------
// layout: [kscq][o][j], element = W[c = kscq*8 + j][o]
__global__ __launch_bounds__(256) void k_prep(const float* __restrict__ pin_w,
    const float* __restrict__ pout_w, const float* __restrict__ qkv_w,
    const float* __restrict__ proj_w,
    u16* __restrict__ wpk1, u16* __restrict__ wpk2,
    u16* __restrict__ qkv_wpk, u16* __restrict__ proj_wpk)
{
  int i = blockIdx.x*256 + threadIdx.x;
  if (i < 6*4*1024*8){
    int j = i & 7, o = (i >> 3) & 1023, kscq = i >> 13;
    int c = kscq*8 + j;
    wpk1[i] = (o < HID2C) ? f2bf(pin_w[o*DIMC + c]) : (u16)0;
  }
  if (i < 16*4*192*8){
    int j = i & 7, o = (i >> 3) % 192, kscq = (i >> 3) / 192;
    int c = kscq*8 + j;
    wpk2[i] = (c < HIDC) ? f2bf(pout_w[o*HIDC + c]) : (u16)0;
  }
  if (i < 24*576*8){
    int j = i & 7, o = (i >> 3) % 576, kscq = (i >> 3) / 576;
    int c = kscq*8 + j;
    qkv_wpk[i] = f2bf(qkv_w[c*576 + o]);
  }
  if (i < 24*192*8){
    int j = i & 7, o = (i >> 3) % 192, kscq = (i >> 3) / 192;
    int c = kscq*8 + j;
    proj_wpk[i] = f2bf(proj_w[c*192 + o]);
  }
}

// ---------- per-batch sum/sumsq over x ----------
__global__ __launch_bounds__(256) void k_reduce(const float* __restrict__ x,
    double* __restrict__ sum, double* __restrict__ sq)
{
  int b = blockIdx.y;
  const float4* xb = (const float4*)(x + (size_t)b*NPB);
  float ls = 0.f, lq = 0.f;
  int n4 = NPB/4;
  for (int i = blockIdx.x*256 + threadIdx.x; i < n4; i += gridDim.x*256){
    float4 u = xb[i];
    ls += u.x+u.y+u.z+u.w; lq += u.x*u.x + u.y*u.y + u.z*u.z + u.w*u.w;
  }
  __shared__ float rs_[256], rq_[256];
  int tid = threadIdx.x;
  rs_[tid]=ls; rq_[tid]=lq; __syncthreads();
  for (int st=128; st>0; st>>=1){ if (tid<st){ rs_[tid]+=rs_[tid+st]; rq_[tid]+=rq_[tid+st]; } __syncthreads(); }
  if (tid==0){ atomicAdd(&sum[b], (double)rs_[0]); atomicAdd(&sq[b], (double)rq_[0]); }
}

__global__ void k_stats(const double* __restrict__ sum, const double* __restrict__ sq,
                        float* __restrict__ stats)
{
  int t = threadIdx.x;
  if (t < NB){
    double mu = sum[t] / (double)NPB;
    double var = sq[t] / (double)NPB - mu*mu;
    stats[2*t]   = (float)mu;
    stats[2*t+1] = (float)(1.0 / sqrt(var + 1e-5));
  }
}

// ---------- s = silu(temb@w1+b1)@w2+b2 ----------
__global__ __launch_bounds__(256) void k_svec(const float* __restrict__ temb,
    const float* __restrict__ w1, const float* __restrict__ b1,
    const float* __restrict__ w2, const float* __restrict__ b2, float* __restrict__ s)
{
  __shared__ float te[NB*TDIM];
  __shared__ float hid[NB*TDIM];
  int tid = threadIdx.x;
  for (int i = tid; i < NB*TDIM; i += 256) te[i] = temb[i];
  __syncthreads();
  for (int i = tid; i < NB*TDIM; i += 256){
    int b = i >> 7, j = i & 127;
    float a = b1[j];
    for (int c = 0; c < TDIM; c++) a += te[b*TDIM + c]*w1[c*TDIM + j];
    hid[i] = a / (1.f + expf(-a));
  }
  __syncthreads();
  for (int i = tid; i < NB*4*DIMC; i += 256){
    int b = i / 768, o = i % 768;
    float a = b2[o];
    for (int c = 0; c < TDIM; c++) a += hid[b*TDIM + c]*w2[c*768 + o];
    s[i] = a;
  }
}

// ---------- window attention, MFMA qkv/proj, fused gn1+adawm on load ----------
__global__ __launch_bounds__(256) void k_attn(
    const float* __restrict__ x0,
    const float* __restrict__ stats, const float* __restrict__ gg, const float* __restrict__ gb,
    const float* __restrict__ sv,
    const u16* __restrict__ qkv_wpk, const float* __restrict__ qkv_b,
    const u16* __restrict__ proj_wpk, const float* __restrict__ proj_b,
    float* __restrict__ x1out, double* __restrict__ gn2_sum, double* __restrict__ gn2_sq)
{
  __shared__ __align__(16) u16 qkv_bf[16*592];   // [t][o] pitch 592, bf16 (18.9 KB)
  __shared__ __align__(16) u16 xa_bf[3072];      // A-frag tile: xw (phase1-2) then ao (phase3-4)
  float* rs_ = (float*)qkv_bf;                   // epilogue reduction (qkv dead)
  float* rq_ = rs_ + 256;

  int tid = threadIdx.x;
  int blk = xcd_swz();
  int b  = blk >> 12;
  int wy = (blk >> 6) & 63;
  int wx = blk & 63;

  float mu = stats[2*b], rstd = stats[2*b+1];
  const float* sb = sv + b*768;

  // phase 1: load 4x4 window, gn1 + adawm, store as bf16 A-frag (row=token, k=channel)
  for (int l = tid; l < DIMC*4; l += 256){
    int c = l >> 2, q = l & 3;
    int qy = q >> 1, qx = q & 1;
    const float* p = x0 + ((size_t)(b*DIMC + c)*NH + (wy*4 + qy*2))*NW + wx*4 + qx*2;
    float2 t0 = *(const float2*)p;
    float2 t1 = *(const float2*)(p + NW);
    float gc = gg[c], bc = gb[c];
    float n00 = (t0.x-mu)*rstd*gc + bc;
    float n01 = (t0.y-mu)*rstd*gc + bc;
    float n10 = (t1.x-mu)*rstd*gc + bc;
    float n11 = (t1.y-mu)*rstd*gc + bc;
    float ll = (n00+n01+n10+n11)*0.5f*sb[c];
    float hl = (n00-n10+n01-n11)*0.5f*sb[192+c];
    float lh = (n00+n10-n01-n11)*0.5f*sb[384+c];
    float hh = (n00-n10-n01+n11)*0.5f*sb[576+c];
    int cq = c >> 3, j = c & 7;
    int t0i = qy*8 + qx*2;
    xa_bf[(cq*16 + t0i    )*8 + j] = f2bf((ll+hl+lh+hh)*0.5f);
    xa_bf[(cq*16 + t0i + 1)*8 + j] = f2bf((ll+hl-lh-hh)*0.5f);
    xa_bf[(cq*16 + t0i + 4)*8 + j] = f2bf((ll-hl+lh-hh)*0.5f);
    xa_bf[(cq*16 + t0i + 5)*8 + j] = f2bf((ll-hl-lh+hh)*0.5f);
  }
  __syncthreads();

  int wv = tid >> 6, lane = tid & 63;
  int colo = lane & 15, rowg = lane >> 4;

  // phase 2: qkv = xw @ qkv_w + b  (M=16, K=192, N=576; 9 N-tiles per wave)
  {
    const bf16x8* av = (const bf16x8*)xa_bf;
    const bf16x8* bv = (const bf16x8*)qkv_wpk;
    bf16x8 a6[6];
    #pragma unroll
    for (int ks = 0; ks < 6; ks++) a6[ks] = av[(ks*4 + rowg)*16 + colo];
    #pragma unroll
    for (int n3 = 0; n3 < 3; n3++){
      int nt = wv*9 + n3*3;
      f32x4 ac0 = {0.f,0.f,0.f,0.f}, ac1 = {0.f,0.f,0.f,0.f}, ac2 = {0.f,0.f,0.f,0.f};
      #pragma unroll
      for (int ks = 0; ks < 6; ks++){
        const bf16x8* wb = &bv[(ks*4 + rowg)*576 + colo];
        ac0 = __builtin_amdgcn_mfma_f32_16x16x32_bf16(a6[ks], wb[nt*16],     ac0, 0,0,0);
        ac1 = __builtin_amdgcn_mfma_f32_16x16x32_bf16(a6[ks], wb[(nt+1)*16], ac1, 0,0,0);
        ac2 = __builtin_amdgcn_mfma_f32_16x16x32_bf16(a6[ks], wb[(nt+2)*16], ac2, 0,0,0);
      }
      #pragma unroll
      for (int m = 0; m < 3; m++){
        f32x4 ac = (m==0) ? ac0 : (m==1) ? ac1 : ac2;
        int o = (nt+m)*16 + colo;
        float bq = qkv_b[o];
        #pragma unroll
        for (int i = 0; i < 4; i++)
          qkv_bf[(rowg*4 + i)*592 + o] = f2bf(ac[i] + bq);
      }
    }
  }
  __syncthreads();

  // phase 3: attention, 192 threads = (head, q-token, dim-half); shfl_xor(1) completes dots
  if (tid < 192){
    int h = tid / 32, rem = tid % 32, q = rem >> 1, half = rem & 1;
    int cb = h*32 + half*16;
    const u32* qrow = (const u32*)&qkv_bf[q*592 + cb];
    float qv[16];
    #pragma unroll
    for (int m = 0; m < 8; m++){
      u32 u = qrow[m]; qv[2*m] = bf2f((u16)u); qv[2*m+1] = bf2f((u16)(u>>16));
    }
    float sc[16]; float mx = -1e30f;
    for (int kt = 0; kt < 16; kt++){
      const u32* krow = (const u32*)&qkv_bf[kt*592 + 192 + cb];
      float d = 0.f;
      #pragma unroll
      for (int m = 0; m < 8; m++){
        u32 u = krow[m];
        d += qv[2*m]*bf2f((u16)u) + qv[2*m+1]*bf2f((u16)(u>>16));
      }
      d += __shfl_xor(d, 1);
      d *= 0.17677669529663687f;
      sc[kt] = d; mx = fmaxf(mx, d);
    }
    float sum = 0.f;
    #pragma unroll
    for (int kt = 0; kt < 16; kt++){ float e = expf(sc[kt]-mx); sc[kt] = e; sum += e; }
    float inv = 1.f/sum;
    float acc[16];
    #pragma unroll
    for (int m = 0; m < 16; m++) acc[m] = 0.f;
    for (int kt = 0; kt < 16; kt++){
      const u32* vrow = (const u32*)&qkv_bf[kt*592 + 384 + cb];
      float p = sc[kt];
      #pragma unroll
      for (int m = 0; m < 8; m++){
        u32 u = vrow[m];
        acc[2*m]   += p*bf2f((u16)u);
        acc[2*m+1] += p*bf2f((u16)(u>>16));
      }
    }
    // write ao into A-frag layout (aliases dead xw)
    u32* aow = (u32*)xa_bf;
    #pragma unroll
    for (int m = 0; m < 8; m++){
      int c = cb + 2*m;
      int cq = c >> 3, j = c & 7;
      u32 pk = (u32)f2bf(acc[2*m]*inv) | ((u32)f2bf(acc[2*m+1]*inv) << 16);
      aow[((cq*16 + q)*8 + j) >> 1] = pk;
    }
  }
  __syncthreads();

  // phase 4: proj (M=16, K=192, N=192; 3 N-tiles per wave) + residual + gn2 partial
  float lsum = 0.f, lsq = 0.f;
  {
    const bf16x8* av = (const bf16x8*)xa_bf;
    const bf16x8* bv = (const bf16x8*)proj_wpk;
    bf16x8 a6[6];
    #pragma unroll
    for (int ks = 0; ks < 6; ks++) a6[ks] = av[(ks*4 + rowg)*16 + colo];
    int nt = wv*3;
    f32x4 ac0 = {0.f,0.f,0.f,0.f}, ac1 = {0.f,0.f,0.f,0.f}, ac2 = {0.f,0.f,0.f,0.f};
    #pragma unroll
    for (int ks = 0; ks < 6; ks++){
      const bf16x8* wb = &bv[(ks*4 + rowg)*192 + colo];
      ac0 = __builtin_amdgcn_mfma_f32_16x16x32_bf16(a6[ks], wb[nt*16],     ac0, 0,0,0);
      ac1 = __builtin_amdgcn_mfma_f32_16x16x32_bf16(a6[ks], wb[(nt+1)*16], ac1, 0,0,0);
      ac2 = __builtin_amdgcn_mfma_f32_16x16x32_bf16(a6[ks], wb[(nt+2)*16], ac2, 0,0,0);
    }
    int y = wy*4 + rowg;
    #pragma unroll
    for (int m = 0; m < 3; m++){
      f32x4 ac = (m==0) ? ac0 : (m==1) ? ac1 : ac2;
      int o = (nt+m)*16 + colo;
      float pb = proj_b[o];
      size_t addr = ((size_t)(b*DIMC + o)*NH + y)*NW + wx*4;
      float4 xv = *(const float4*)&x0[addr];
      float4 ov;
      ov.x = xv.x + ac[0] + pb;
      ov.y = xv.y + ac[1] + pb;
      ov.z = xv.z + ac[2] + pb;
      ov.w = xv.w + ac[3] + pb;
      *(float4*)&x1out[addr] = ov;
      lsum += ov.x+ov.y+ov.z+ov.w;
      lsq  += ov.x*ov.x + ov.y*ov.y + ov.z*ov.z + ov.w*ov.w;
    }
  }
  rs_[tid] = lsum; rq_[tid] = lsq;
  __syncthreads();
  for (int st = 128; st > 0; st >>= 1){
    if (tid < st){ rs_[tid] += rs_[tid+st]; rq_[tid] += rq_[tid+st]; }
    __syncthreads();
  }
  if (tid == 0){
    atomicAdd(&gn2_sum[b], (double)rs_[0]);
    atomicAdd(&gn2_sq[b], (double)rq_[0]);
  }
}

// ---------- gdfn stage 1: fused gn2+adawm + MFMA pointwise 192->1020 into strip T (bf16)
__global__ __launch_bounds__(256) void k_pin(
    const float* __restrict__ x1, const float* __restrict__ stats,
    const float* __restrict__ gg, const float* __restrict__ gb, const float* __restrict__ sv,
    const u16* __restrict__ wpk1, const float* __restrict__ pin_b,
    u16* __restrict__ T, int s, int strip, int trows)
{
  __shared__ __align__(16) u16 pxb[24*16*8];   // 6 KB
  int tid = threadIdx.x;
  int virt = xcd_swz();
  int xc = virt & 15;
  int rb = virt >> 4;
  int r = rb % trows;
  int b = rb / trows;
  int y = s*strip - 1 + r;
  int x0 = xc*16;
  u16* Trow = T + ((size_t)(b*trows + r)*NW + x0)*HID2C;
  bool valid = (y >= 0) && (y < NH);
  if (!valid){
    for (int l = tid; l < 16*HID2C; l += 256) Trow[l] = 0;
    return;
  }
  float mu = stats[2*b], rstd = stats[2*b+1];
  const float* sb = sv + b*768;
  int ytop = y & ~1;
  bool istop = (y == ytop);
  for (int l = tid; l < DIMC*8; l += 256){
    int c = l >> 3, u = l & 7;
    const float* p = x1 + ((size_t)(b*DIMC + c)*NH + ytop)*NW + x0 + 2*u;
    float2 t0 = *(const float2*)p;
    float2 t1 = *(const float2*)(p + NW);
    float gc = gg[c], bc = gb[c];
    float n00 = (t0.x-mu)*rstd*gc + bc;
    float n01 = (t0.y-mu)*rstd*gc + bc;
    float n10 = (t1.x-mu)*rstd*gc + bc;
    float n11 = (t1.y-mu)*rstd*gc + bc;
    float ll = (n00+n01+n10+n11)*0.5f*sb[c];
    float hl = (n00-n10+n01-n11)*0.5f*sb[192+c];
    float lh = (n00+n10-n01-n11)*0.5f*sb[384+c];
    float hh = (n00-n10-n01+n11)*0.5f*sb[576+c];
    float v0, v1;
    if (istop){ v0 = (ll+hl+lh+hh)*0.5f; v1 = (ll+hl-lh-hh)*0.5f; }
    else      { v0 = (ll-hl+lh-hh)*0.5f; v1 = (ll-hl-lh+hh)*0.5f; }
    int cq = c >> 3, j = c & 7;
    pxb[((cq*16 + 2*u)*8) + j]     = f2bf(v0);
    pxb[((cq*16 + 2*u + 1)*8) + j] = f2bf(v1);
  }
  __syncthreads();

  int wv = tid >> 6, lane = tid & 63;
  int colo = lane & 15, rowg = lane >> 4;
  const bf16x8* pxv = (const bf16x8*)pxb;
  const bf16x8* wv1 = (const bf16x8*)wpk1;
  bf16x8 a6[6];
  #pragma unroll
  for (int ks = 0; ks < 6; ks++)
    a6[ks] = pxv[(ks*4 + rowg)*16 + colo];
  for (int nt16 = 0; nt16 < 16; nt16++){
    int nt = wv*16 + nt16;
    f32x4 acc = {0.f, 0.f, 0.f, 0.f};
    #pragma unroll
    for (int ks = 0; ks < 6; ks++)
      acc = __builtin_amdgcn_mfma_f32_16x16x32_bf16(a6[ks],
              wv1[(ks*4 + rowg)*1024 + nt*16 + colo], acc, 0, 0, 0);
    int o = nt*16 + colo;
    if (o < HID2C){
      float pb = pin_b[o];
      #pragma unroll
      for (int i = 0; i < 4; i++)
        Trow[(size_t)(rowg*4 + i)*HID2C + o] = f2bf(acc[i] + pb);
    }
  }
}

// ---------- gdfn stage 2: depthwise 3x3 + gelu-gate (scalar) + MFMA pout 512->192
#define DW_TAPS(XGUARD)                                                          \
  _Pragma("unroll")                                                              \
  for (int dy = 0; dy < 3; dy++){                                                \
    const u16* Tr = Tbase + (size_t)dy*NW*HID2C;                                 \
    _Pragma("unroll")                                                            \
    for (int dx = -1; dx <= 1; dx++){                                            \
      int xx = gx + dx;                                                          \
      XGUARD                                                                     \
      int wi = dy*3 + (dx+1);                                                    \
      const u16* pp = Tr + (size_t)xx*HID2C + c0;                                \
      unsigned int lo = *(const unsigned int*)pp;                                \
      unsigned int hi = *(const unsigned int*)(pp + HIDC);                       \
      a0 += wA[wi]*bf2f((u16)lo);  a1 += wB[wi]*bf2f((u16)(lo>>16));             \
      a2 += wC[wi]*bf2f((u16)hi);  a3 += wD[wi]*bf2f((u16)(hi>>16));             \
    }                                                                            \
  }

__global__ __launch_bounds__(256) void k_dwgate(
    const u16* __restrict__ T, const u16* __restrict__ wpk2,
    const float* __restrict__ dw_w, const float* __restrict__ dw_b,
    const float* __restrict__ pout_b, u16* __restrict__ G,
    float* __restrict__ se_sum, int s, int strip, int trows)
{
  __shared__ __align__(16) u16 gbuf[16*512];   // 16 KB, A-frag friendly [p][c]
  int tid = threadIdx.x;
  int virt = xcd_swz();
  int xc = virt & 15;
  int rb = virt >> 4;
  int ry = rb % strip;
  int b = rb / strip;
  int y = s*strip + ry;
  int x0 = xc*16;
  int r = ry + 1;
  if (tid < 255){
    int c0 = 2*tid;
    float wA[9], wB[9], wC[9], wD[9];
    #pragma unroll
    for (int t9 = 0; t9 < 9; t9++){
      wA[t9] = dw_w[c0*9+t9];          wB[t9] = dw_w[(c0+1)*9+t9];
      wC[t9] = dw_w[(c0+HIDC)*9+t9];   wD[t9] = dw_w[(c0+HIDC+1)*9+t9];
    }
    float dbA = dw_b[c0], dbB = dw_b[c0+1], dbC = dw_b[c0+HIDC], dbD = dw_b[c0+HIDC+1];
    const u16* Tbase = T + (size_t)(b*trows + r - 1)*NW*HID2C;
    bool interior = (x0 > 0) && (x0 + 16 < NW);
    if (interior){
      for (int p = 0; p < 16; p++){
        int gx = x0 + p;
        float a0=dbA, a1=dbB, a2=dbC, a3=dbD;
        DW_TAPS()
        float geA = 0.5f*a0*(1.f + erff(a0*0.70710678118654752f));
        float geB = 0.5f*a1*(1.f + erff(a1*0.70710678118654752f));
        u32 pk = (u32)f2bf(geA*a2) | ((u32)f2bf(geB*a3) << 16);
        *(u32*)&gbuf[p*512 + c0] = pk;
      }
    } else {
      for (int p = 0; p < 16; p++){
        int gx = x0 + p;
        float a0=dbA, a1=dbB, a2=dbC, a3=dbD;
        DW_TAPS(if (xx < 0 || xx >= NW) continue;)
        float geA = 0.5f*a0*(1.f + erff(a0*0.70710678118654752f));
        float geB = 0.5f*a1*(1.f + erff(a1*0.70710678118654752f));
        u32 pk = (u32)f2bf(geA*a2) | ((u32)f2bf(geB*a3) << 16);
        *(u32*)&gbuf[p*512 + c0] = pk;
      }
    }
  } else {
    for (int p = 0; p < 16; p++) *(u32*)&gbuf[p*512 + 510] = 0;
  }
  __syncthreads();

  int wv = tid >> 6, lane = tid & 63;
  int colo = lane & 15, rowg = lane >> 4;
  const bf16x8* gv = (const bf16x8*)gbuf;
  const bf16x8* wv2 = (const bf16x8*)wpk2;
  f32x4 acc0 = {0.f,0.f,0.f,0.f}, acc1 = {0.f,0.f,0.f,0.f}, acc2 = {0.f,0.f,0.f,0.f};
  int nt0 = wv*3;
  for (int ks = 0; ks < 16; ks++){
    bf16x8 a = gv[colo*64 + ks*4 + rowg];
    const bf16x8* wb = &wv2[(ks*4 + rowg)*192 + colo];
    acc0 = __builtin_amdgcn_mfma_f32_16x16x32_bf16(a, wb[nt0*16],       acc0, 0,0,0);
    acc1 = __builtin_amdgcn_mfma_f32_16x16x32_bf16(a, wb[(nt0+1)*16],   acc1, 0,0,0);
    acc2 = __builtin_amdgcn_mfma_f32_16x16x32_bf16(a, wb[(nt0+2)*16],   acc2, 0,0,0);
  }
  #pragma unroll
  for (int n3 = 0; n3 < 3; n3++){
    f32x4 acc = (n3==0) ? acc0 : (n3==1) ? acc1 : acc2;
    int o = (nt0 + n3)*16 + colo;
    float pb = pout_b[o];
    float v0 = acc[0]+pb, v1 = acc[1]+pb, v2 = acc[2]+pb, v3 = acc[3]+pb;
    ushort4 ov; ov.x = f2bf(v0); ov.y = f2bf(v1); ov.z = f2bf(v2); ov.w = f2bf(v3);
    u16* Gp = G + ((size_t)(b*DIMC + o)*NH + y)*NW + x0 + rowg*4;
    *(ushort4*)Gp = ov;
    float part = v0+v1+v2+v3;
    part += __shfl_xor(part, 16);
    part += __shfl_xor(part, 32);
    if (rowg == 0) atomicAdd(&se_sum[b*DIMC + o], part);
  }
}

// ---------- SE gate vector ----------
__global__ __launch_bounds__(256) void k_se(const float* __restrict__ se_sum,
    const float* __restrict__ w1, const float* __restrict__ w2, float* __restrict__ sey)
{
  __shared__ float mean[NB*DIMC];
  __shared__ float hid[NB*REDC];
  int tid = threadIdx.x;
  for (int i = tid; i < NB*DIMC; i += 256) mean[i] = se_sum[i] * (1.f/(float)HW);
  __syncthreads();
  for (int i = tid; i < NB*REDC; i += 256){
    int b = i / REDC, rr = i % REDC;
    float a = 0.f;
    for (int c = 0; c < DIMC; c++) a += mean[b*DIMC + c]*w1[c*REDC + rr];
    hid[i] = fmaxf(a, 0.f);
  }
  __syncthreads();
  for (int i = tid; i < NB*DIMC; i += 256){
    int b = i / DIMC, o = i % DIMC;
    float a = 0.f;
    for (int rr = 0; rr < REDC; rr++) a += hid[b*REDC + rr]*w2[rr*DIMC + o];
    sey[i] = 1.f/(1.f + expf(-a));
  }
}

// ---------- final: out = x1 + G * sey ----------
__global__ __launch_bounds__(256) void k_final(const u16* __restrict__ G,
    const float* __restrict__ sey, float* __restrict__ xout)
{
  int i4 = blockIdx.x*256 + threadIdx.x;
  int cpix = i4 >> 14;              // b*DIMC + c
  float sc = sey[cpix];
  ushort4 gv = *(const ushort4*)&G[(size_t)i4*4];
  float4 xv = *(const float4*)&xout[(size_t)i4*4];
  float4 ov;
  ov.x = xv.x + bf2f(gv.x)*sc;
  ov.y = xv.y + bf2f(gv.y)*sc;
  ov.z = xv.z + bf2f(gv.z)*sc;
  ov.w = xv.w + bf2f(gv.w)*sc;
  *(float4*)&xout[(size_t)i4*4] = ov;
}

extern "C" void kernel_launch(void* const* d_in, const int* in_sizes, int n_in,
                              void* d_out, int out_size, void* d_ws, size_t ws_size,
                              hipStream_t stream)
{
  const float* x      = (const float*)d_in[0];
  const float* temb   = (const float*)d_in[1];
  const float* gn1_g  = (const float*)d_in[2];
  const float* gn1_b  = (const float*)d_in[3];
  const float* aw1_w1 = (const float*)d_in[4];
  const float* aw1_b1 = (const float*)d_in[5];
  const float* aw1_w2 = (const float*)d_in[6];
  const float* aw1_b2 = (const float*)d_in[7];
  const float* qkv_w  = (const float*)d_in[8];
  const float* qkv_b  = (const float*)d_in[9];
  const float* proj_w = (const float*)d_in[10];
  const float* proj_b = (const float*)d_in[11];
  const float* gn2_g  = (const float*)d_in[12];
  const float* gn2_b  = (const float*)d_in[13];
  const float* aw2_w1 = (const float*)d_in[14];
  const float* aw2_b1 = (const float*)d_in[15];
  const float* aw2_w2 = (const float*)d_in[16];
  const float* aw2_b2 = (const float*)d_in[17];
  const float* pin_w  = (const float*)d_in[18];
  const float* pin_b  = (const float*)d_in[19];
  const float* dw_w   = (const float*)d_in[20];
  const float* dw_b   = (const float*)d_in[21];
  const float* pout_w = (const float*)d_in[22];
  const float* pout_b = (const float*)d_in[23];
  const float* se_w1  = (const float*)d_in[24];
  const float* se_w2  = (const float*)d_in[25];

  unsigned char* ws = (unsigned char*)d_ws;
  // scalars/atomics block (zeroed each launch): 16 doubles + 768 floats = 3200 B
  double* gn1_sum = (double*)ws;
  double* gn1_sq  = gn1_sum + 4;
  double* gn2_sum = gn1_sum + 8;
  double* gn2_sq  = gn1_sum + 12;
  float*  se_sumf = (float*)(ws + 128);
  float*  fbase   = (float*)(ws + 3200);
  float* s1      = fbase;                        // 3072
  float* s2      = s1 + 3072;                    // 3072
  float* stats1  = s2 + 3072;                    // 8
  float* stats2  = stats1 + 8;                   // 8
  float* sey     = stats2 + 8;                   // 768 -> floats end at 30912
  u16* wpk1     = (u16*)(ws + 30976);            // 196608 u16 = 393216 B
  u16* wpk2     = (u16*)(ws + 424192);           // 98304 u16 = 196608 B
  u16* qkv_wpk  = (u16*)(ws + 620800);           // 110592 u16 = 221184 B
  u16* proj_wpk = (u16*)(ws + 841984);           // 36864 u16 = 73728 B -> ends 915712
  size_t offG = 915712;                          // 256-aligned
  u16* G  = (u16*)(ws + offG);                   // 100.7 MB
  size_t offT = offG + (size_t)NB*DIMC*HW*2;
  u16* Tb = (u16*)(ws + offT);

  // pick largest strip that fits the workspace
  int S = 256;
  while (S > 16 && ws_size < offT + (size_t)NB*(S+2)*NW*HID2C*2) S >>= 1;
  int trows = S + 2;
  int nstrips = NH / S;

  float* x1 = (float*)d_out;

  hipMemsetAsync(ws, 0, 3200, stream);
  k_prep<<<768, 256, 0, stream>>>(pin_w, pout_w, qkv_w, proj_w, wpk1, wpk2, qkv_wpk, proj_wpk);
  k_reduce<<<dim3(1024,4), 256, 0, stream>>>(x, gn1_sum, gn1_sq);
  k_stats<<<1, 64, 0, stream>>>(gn1_sum, gn1_sq, stats1);
  k_svec<<<1, 256, 0, stream>>>(temb, aw1_w1, aw1_b1, aw1_w2, aw1_b2, s1);
  k_svec<<<1, 256, 0, stream>>>(temb, aw2_w1, aw2_b1, aw2_w2, aw2_b2, s2);
  k_attn<<<16384, 256, 0, stream>>>(x, stats1, gn1_g, gn1_b, s1,
                                    qkv_wpk, qkv_b, proj_wpk, proj_b, x1, gn2_sum, gn2_sq);
  k_stats<<<1, 64, 0, stream>>>(gn2_sum, gn2_sq, stats2);
  for (int s = 0; s < nstrips; s++){
    k_pin<<<16*trows*NB, 256, 0, stream>>>(x1, stats2, gn2_g, gn2_b, s2,
                                           wpk1, pin_b, Tb, s, S, trows);
    k_dwgate<<<16*S*NB, 256, 0, stream>>>(Tb, wpk2, dw_w, dw_b, pout_b, G, se_sumf, s, S, trows);
  }
  k_se<<<1, 256, 0, stream>>>(se_sumf, se_w1, se_w2, sey);
  k_final<<<49152, 256, 0, stream>>>(G, sey, x1);
}

// Round 5
// 1999.140 us; speedup vs baseline: 15.0904x; 1.2584x over previous
//
#include <hip/hip_runtime.h>
#include <hip/hip_bf16.h>
#include <cmath>

#define DIMC 192
#define NHEAD 6
#define HDIM 32
#define TDIM 128
#define HIDC 510
#define HID2C 1020
#define REDC 24
#define NB 4
#define NH 256
#define NW 256
#define HW 65536
#define NPB (DIMC*HW)

typedef unsigned short u16;
typedef unsigned int u32;
typedef short bf16x8 __attribute__((ext_vector_type(8)));
typedef float f32x4 __attribute__((ext_vector_type(4)));

__device__ __forceinline__ float bf2f(u16 u){
  union { unsigned int i; float f; } v; v.i = ((unsigned int)u) << 16; return v.f;
}
__device__ __forceinline__ u16 f2bf(float f){
  union { float f; unsigned int i; } v; v.f = f;
  unsigned int i = v.i;
  return (u16)((i + 0x7FFFu + ((i >> 16) & 1u)) >> 16);
}
// XCD-chunked bijective swizzle (requires gridDim.x % 8 == 0)
__device__ __forceinline__ int xcd_swz(){
  int n = gridDim.x, l = blockIdx.x;
  return (l & 7)*(n >> 3) + (l >> 3);
}

// ---------- pack pin_w / pout_w / qkv_w / proj_w into MFMA B-fragment bf16 layouts ----------
// layout: [kscq][o][j], element = W[c = kscq*8 + j][o]
__global__ __launch_bounds__(256) void k_prep(const float* __restrict__ pin_w,
    const float* __restrict__ pout_w, const float* __restrict__ qkv_w,
    const float* __restrict__ proj_w,
    u16* __restrict__ wpk1, u16* __restrict__ wpk2,
    u16* __restrict__ qkv_wpk, u16* __restrict__ proj_wpk)
{
  int i = blockIdx.x*256 + threadIdx.x;
  if (i < 6*4*1024*8){
    int j = i & 7, o = (i >> 3) & 1023, kscq = i >> 13;
    int c = kscq*8 + j;
    wpk1[i] = (o < HID2C) ? f2bf(pin_w[o*DIMC + c]) : (u16)0;
  }
  if (i < 16*4*192*8){
    int j = i & 7, o = (i >> 3) % 192, kscq = (i >> 3) / 192;
    int c = kscq*8 + j;
    wpk2[i] = (c < HIDC) ? f2bf(pout_w[o*HIDC + c]) : (u16)0;
  }
  if (i < 24*576*8){
    int j = i & 7, o = (i >> 3) % 576, kscq = (i >> 3) / 576;
    int c = kscq*8 + j;
    qkv_wpk[i] = f2bf(qkv_w[c*576 + o]);
  }
  if (i < 24*192*8){
    int j = i & 7, o = (i >> 3) % 192, kscq = (i >> 3) / 192;
    int c = kscq*8 + j;
    proj_wpk[i] = f2bf(proj_w[c*192 + o]);
  }
}

// ---------- per-batch sum/sumsq over x ----------
__global__ __launch_bounds__(256) void k_reduce(const float* __restrict__ x,
    double* __restrict__ sum, double* __restrict__ sq)
{
  int b = blockIdx.y;
  const float4* xb = (const float4*)(x + (size_t)b*NPB);
  float ls = 0.f, lq = 0.f;
  int n4 = NPB/4;
  for (int i = blockIdx.x*256 + threadIdx.x; i < n4; i += gridDim.x*256){
    float4 u = xb[i];
    ls += u.x+u.y+u.z+u.w; lq += u.x*u.x + u.y*u.y + u.z*u.z + u.w*u.w;
  }
  __shared__ float rs_[256], rq_[256];
  int tid = threadIdx.x;
  rs_[tid]=ls; rq_[tid]=lq; __syncthreads();
  for (int st=128; st>0; st>>=1){ if (tid<st){ rs_[tid]+=rs_[tid+st]; rq_[tid]+=rq_[tid+st]; } __syncthreads(); }
  if (tid==0){ atomicAdd(&sum[b], (double)rs_[0]); atomicAdd(&sq[b], (double)rq_[0]); }
}

__global__ void k_stats(const double* __restrict__ sum, const double* __restrict__ sq,
                        float* __restrict__ stats)
{
  int t = threadIdx.x;
  if (t < NB){
    double mu = sum[t] / (double)NPB;
    double var = sq[t] / (double)NPB - mu*mu;
    stats[2*t]   = (float)mu;
    stats[2*t+1] = (float)(1.0 / sqrt(var + 1e-5));
  }
}

// ---------- s = silu(temb@w1+b1)@w2+b2 ----------
__global__ __launch_bounds__(256) void k_svec(const float* __restrict__ temb,
    const float* __restrict__ w1, const float* __restrict__ b1,
    const float* __restrict__ w2, const float* __restrict__ b2, float* __restrict__ s)
{
  __shared__ float te[NB*TDIM];
  __shared__ float hid[NB*TDIM];
  int tid = threadIdx.x;
  for (int i = tid; i < NB*TDIM; i += 256) te[i] = temb[i];
  __syncthreads();
  for (int i = tid; i < NB*TDIM; i += 256){
    int b = i >> 7, j = i & 127;
    float a = b1[j];
    for (int c = 0; c < TDIM; c++) a += te[b*TDIM + c]*w1[c*TDIM + j];
    hid[i] = a / (1.f + expf(-a));
  }
  __syncthreads();
  for (int i = tid; i < NB*4*DIMC; i += 256){
    int b = i / 768, o = i % 768;
    float a = b2[o];
    for (int c = 0; c < TDIM; c++) a += hid[b*TDIM + c]*w2[c*768 + o];
    s[i] = a;
  }
}

// ---------- window attention, MFMA qkv/proj, fused gn1+adawm on load ----------
__global__ __launch_bounds__(256) void k_attn(
    const float* __restrict__ x0,
    const float* __restrict__ stats, const float* __restrict__ gg, const float* __restrict__ gb,
    const float* __restrict__ sv,
    const u16* __restrict__ qkv_wpk, const float* __restrict__ qkv_b,
    const u16* __restrict__ proj_wpk, const float* __restrict__ proj_b,
    float* __restrict__ x1out, double* __restrict__ gn2_sum, double* __restrict__ gn2_sq)
{
  __shared__ __align__(16) u16 qkv_bf[16*592];   // [t][o] pitch 592, bf16 (18.9 KB)
  __shared__ __align__(16) u16 xa_bf[3072];      // A-frag tile: xw (phase1-2) then ao (phase3-4)
  float* rs_ = (float*)qkv_bf;                   // epilogue reduction (qkv dead)
  float* rq_ = rs_ + 256;

  int tid = threadIdx.x;
  int blk = xcd_swz();
  int b  = blk >> 12;
  int wy = (blk >> 6) & 63;
  int wx = blk & 63;

  float mu = stats[2*b], rstd = stats[2*b+1];
  const float* sb = sv + b*768;

  // phase 1: load 4x4 window, gn1 + adawm, store as bf16 A-frag (row=token, k=channel)
  for (int l = tid; l < DIMC*4; l += 256){
    int c = l >> 2, q = l & 3;
    int qy = q >> 1, qx = q & 1;
    const float* p = x0 + ((size_t)(b*DIMC + c)*NH + (wy*4 + qy*2))*NW + wx*4 + qx*2;
    float2 t0 = *(const float2*)p;
    float2 t1 = *(const float2*)(p + NW);
    float gc = gg[c], bc = gb[c];
    float n00 = (t0.x-mu)*rstd*gc + bc;
    float n01 = (t0.y-mu)*rstd*gc + bc;
    float n10 = (t1.x-mu)*rstd*gc + bc;
    float n11 = (t1.y-mu)*rstd*gc + bc;
    float ll = (n00+n01+n10+n11)*0.5f*sb[c];
    float hl = (n00-n10+n01-n11)*0.5f*sb[192+c];
    float lh = (n00+n10-n01-n11)*0.5f*sb[384+c];
    float hh = (n00-n10-n01+n11)*0.5f*sb[576+c];
    int cq = c >> 3, j = c & 7;
    int t0i = qy*8 + qx*2;
    xa_bf[(cq*16 + t0i    )*8 + j] = f2bf((ll+hl+lh+hh)*0.5f);
    xa_bf[(cq*16 + t0i + 1)*8 + j] = f2bf((ll+hl-lh-hh)*0.5f);
    xa_bf[(cq*16 + t0i + 4)*8 + j] = f2bf((ll-hl+lh-hh)*0.5f);
    xa_bf[(cq*16 + t0i + 5)*8 + j] = f2bf((ll-hl-lh+hh)*0.5f);
  }
  __syncthreads();

  int wv = tid >> 6, lane = tid & 63;
  int colo = lane & 15, rowg = lane >> 4;

  // phase 2: qkv = xw @ qkv_w + b  (M=16, K=192, N=576; 9 N-tiles per wave)
  {
    const bf16x8* av = (const bf16x8*)xa_bf;
    const bf16x8* bv = (const bf16x8*)qkv_wpk;
    bf16x8 a6[6];
    #pragma unroll
    for (int ks = 0; ks < 6; ks++) a6[ks] = av[(ks*4 + rowg)*16 + colo];
    #pragma unroll
    for (int n3 = 0; n3 < 3; n3++){
      int nt = wv*9 + n3*3;
      f32x4 ac0 = {0.f,0.f,0.f,0.f}, ac1 = {0.f,0.f,0.f,0.f}, ac2 = {0.f,0.f,0.f,0.f};
      #pragma unroll
      for (int ks = 0; ks < 6; ks++){
        const bf16x8* wb = &bv[(ks*4 + rowg)*576 + colo];
        ac0 = __builtin_amdgcn_mfma_f32_16x16x32_bf16(a6[ks], wb[nt*16],     ac0, 0,0,0);
        ac1 = __builtin_amdgcn_mfma_f32_16x16x32_bf16(a6[ks], wb[(nt+1)*16], ac1, 0,0,0);
        ac2 = __builtin_amdgcn_mfma_f32_16x16x32_bf16(a6[ks], wb[(nt+2)*16], ac2, 0,0,0);
      }
      #pragma unroll
      for (int m = 0; m < 3; m++){
        f32x4 ac = (m==0) ? ac0 : (m==1) ? ac1 : ac2;
        int o = (nt+m)*16 + colo;
        float bq = qkv_b[o];
        #pragma unroll
        for (int i = 0; i < 4; i++)
          qkv_bf[(rowg*4 + i)*592 + o] = f2bf(ac[i] + bq);
      }
    }
  }
  __syncthreads();

  // phase 3: attention, 192 threads = (head, q-token, dim-half); shfl_xor(1) completes dots
  if (tid < 192){
    int h = tid / 32, rem = tid % 32, q = rem >> 1, half = rem & 1;
    int cb = h*32 + half*16;
    const u32* qrow = (const u32*)&qkv_bf[q*592 + cb];
    float qv[16];
    #pragma unroll
    for (int m = 0; m < 8; m++){
      u32 u = qrow[m]; qv[2*m] = bf2f((u16)u); qv[2*m+1] = bf2f((u16)(u>>16));
    }
    float sc[16]; float mx = -1e30f;
    for (int kt = 0; kt < 16; kt++){
      const u32* krow = (const u32*)&qkv_bf[kt*592 + 192 + cb];
      float d = 0.f;
      #pragma unroll
      for (int m = 0; m < 8; m++){
        u32 u = krow[m];
        d += qv[2*m]*bf2f((u16)u) + qv[2*m+1]*bf2f((u16)(u>>16));
      }
      d += __shfl_xor(d, 1);
      d *= 0.17677669529663687f;
      sc[kt] = d; mx = fmaxf(mx, d);
    }
    float sum = 0.f;
    #pragma unroll
    for (int kt = 0; kt < 16; kt++){ float e = expf(sc[kt]-mx); sc[kt] = e; sum += e; }
    float inv = 1.f/sum;
    float acc[16];
    #pragma unroll
    for (int m = 0; m < 16; m++) acc[m] = 0.f;
    for (int kt = 0; kt < 16; kt++){
      const u32* vrow = (const u32*)&qkv_bf[kt*592 + 384 + cb];
      float p = sc[kt];
      #pragma unroll
      for (int m = 0; m < 8; m++){
        u32 u = vrow[m];
        acc[2*m]   += p*bf2f((u16)u);
        acc[2*m+1] += p*bf2f((u16)(u>>16));
      }
    }
    // write ao into A-frag layout (aliases dead xw)
    u32* aow = (u32*)xa_bf;
    #pragma unroll
    for (int m = 0; m < 8; m++){
      int c = cb + 2*m;
      int cq = c >> 3, j = c & 7;
      u32 pk = (u32)f2bf(acc[2*m]*inv) | ((u32)f2bf(acc[2*m+1]*inv) << 16);
      aow[((cq*16 + q)*8 + j) >> 1] = pk;
    }
  }
  __syncthreads();

  // phase 4: proj (M=16, K=192, N=192; 3 N-tiles per wave) + residual + gn2 partial
  float lsum = 0.f, lsq = 0.f;
  {
    const bf16x8* av = (const bf16x8*)xa_bf;
    const bf16x8* bv = (const bf16x8*)proj_wpk;
    bf16x8 a6[6];
    #pragma unroll
    for (int ks = 0; ks < 6; ks++) a6[ks] = av[(ks*4 + rowg)*16 + colo];
    int nt = wv*3;
    f32x4 ac0 = {0.f,0.f,0.f,0.f}, ac1 = {0.f,0.f,0.f,0.f}, ac2 = {0.f,0.f,0.f,0.f};
    #pragma unroll
    for (int ks = 0; ks < 6; ks++){
      const bf16x8* wb = &bv[(ks*4 + rowg)*192 + colo];
      ac0 = __builtin_amdgcn_mfma_f32_16x16x32_bf16(a6[ks], wb[nt*16],     ac0, 0,0,0);
      ac1 = __builtin_amdgcn_mfma_f32_16x16x32_bf16(a6[ks], wb[(nt+1)*16], ac1, 0,0,0);
      ac2 = __builtin_amdgcn_mfma_f32_16x16x32_bf16(a6[ks], wb[(nt+2)*16], ac2, 0,0,0);
    }
    int y = wy*4 + rowg;
    #pragma unroll
    for (int m = 0; m < 3; m++){
      f32x4 ac = (m==0) ? ac0 : (m==1) ? ac1 : ac2;
      int o = (nt+m)*16 + colo;
      float pb = proj_b[o];
      size_t addr = ((size_t)(b*DIMC + o)*NH + y)*NW + wx*4;
      float4 xv = *(const float4*)&x0[addr];
      float4 ov;
      ov.x = xv.x + ac[0] + pb;
      ov.y = xv.y + ac[1] + pb;
      ov.z = xv.z + ac[2] + pb;
      ov.w = xv.w + ac[3] + pb;
      *(float4*)&x1out[addr] = ov;
      lsum += ov.x+ov.y+ov.z+ov.w;
      lsq  += ov.x*ov.x + ov.y*ov.y + ov.z*ov.z + ov.w*ov.w;
    }
  }
  rs_[tid] = lsum; rq_[tid] = lsq;
  __syncthreads();
  for (int st = 128; st > 0; st >>= 1){
    if (tid < st){ rs_[tid] += rs_[tid+st]; rq_[tid] += rq_[tid+st]; }
    __syncthreads();
  }
  if (tid == 0){
    atomicAdd(&gn2_sum[b], (double)rs_[0]);
    atomicAdd(&gn2_sq[b], (double)rq_[0]);
  }
}

// ---------- gdfn stage 1: fused gn2+adawm + MFMA pointwise 192->1020 into strip T (bf16)
__global__ __launch_bounds__(256) void k_pin(
    const float* __restrict__ x1, const float* __restrict__ stats,
    const float* __restrict__ gg, const float* __restrict__ gb, const float* __restrict__ sv,
    const u16* __restrict__ wpk1, const float* __restrict__ pin_b,
    u16* __restrict__ T, int s, int strip, int trows)
{
  __shared__ __align__(16) u16 pxb[24*16*8];   // 6 KB
  int tid = threadIdx.x;
  int virt = xcd_swz();
  int xc = virt & 15;
  int rb = virt >> 4;
  int r = rb % trows;
  int b = rb / trows;
  int y = s*strip - 1 + r;
  int x0 = xc*16;
  u16* Trow = T + ((size_t)(b*trows + r)*NW + x0)*HID2C;
  bool valid = (y >= 0) && (y < NH);
  if (!valid){
    for (int l = tid; l < 16*HID2C; l += 256) Trow[l] = 0;
    return;
  }
  float mu = stats[2*b], rstd = stats[2*b+1];
  const float* sb = sv + b*768;
  int ytop = y & ~1;
  bool istop = (y == ytop);
  for (int l = tid; l < DIMC*8; l += 256){
    int c = l >> 3, u = l & 7;
    const float* p = x1 + ((size_t)(b*DIMC + c)*NH + ytop)*NW + x0 + 2*u;
    float2 t0 = *(const float2*)p;
    float2 t1 = *(const float2*)(p + NW);
    float gc = gg[c], bc = gb[c];
    float n00 = (t0.x-mu)*rstd*gc + bc;
    float n01 = (t0.y-mu)*rstd*gc + bc;
    float n10 = (t1.x-mu)*rstd*gc + bc;
    float n11 = (t1.y-mu)*rstd*gc + bc;
    float ll = (n00+n01+n10+n11)*0.5f*sb[c];
    float hl = (n00-n10+n01-n11)*0.5f*sb[192+c];
    float lh = (n00+n10-n01-n11)*0.5f*sb[384+c];
    float hh = (n00-n10-n01+n11)*0.5f*sb[576+c];
    float v0, v1;
    if (istop){ v0 = (ll+hl+lh+hh)*0.5f; v1 = (ll+hl-lh-hh)*0.5f; }
    else      { v0 = (ll-hl+lh-hh)*0.5f; v1 = (ll-hl-lh+hh)*0.5f; }
    int cq = c >> 3, j = c & 7;
    pxb[((cq*16 + 2*u)*8) + j]     = f2bf(v0);
    pxb[((cq*16 + 2*u + 1)*8) + j] = f2bf(v1);
  }
  __syncthreads();

  int wv = tid >> 6, lane = tid & 63;
  int colo = lane & 15, rowg = lane >> 4;
  const bf16x8* pxv = (const bf16x8*)pxb;
  const bf16x8* wv1 = (const bf16x8*)wpk1;
  bf16x8 a6[6];
  #pragma unroll
  for (int ks = 0; ks < 6; ks++)
    a6[ks] = pxv[(ks*4 + rowg)*16 + colo];
  for (int nt16 = 0; nt16 < 16; nt16++){
    int nt = wv*16 + nt16;
    f32x4 acc = {0.f, 0.f, 0.f, 0.f};
    #pragma unroll
    for (int ks = 0; ks < 6; ks++)
      acc = __builtin_amdgcn_mfma_f32_16x16x32_bf16(a6[ks],
              wv1[(ks*4 + rowg)*1024 + nt*16 + colo], acc, 0, 0, 0);
    int o = nt*16 + colo;
    if (o < HID2C){
      float pb = pin_b[o];
      #pragma unroll
      for (int i = 0; i < 4; i++)
        Trow[(size_t)(rowg*4 + i)*HID2C + o] = f2bf(acc[i] + pb);
    }
  }
}

// ---------- gdfn stage 2: sliding-window depthwise 3x3 + gelu-gate + MFMA pout 512->192
// gbuf is XOR-swizzled: u16 index p*512 + (c ^ ((p&7)<<3)); read octet (ks*4+rowg)^(colo&7)
__global__ __launch_bounds__(256, 3) void k_dwgate(
    const u16* __restrict__ T, const u16* __restrict__ wpk2,
    const float* __restrict__ dw_w, const float* __restrict__ dw_b,
    const float* __restrict__ pout_b, u16* __restrict__ G,
    float* __restrict__ se_sum, int s, int strip, int trows)
{
  __shared__ __align__(16) u16 gbuf[16*512];   // 16 KB, swizzled [p][c]
  int tid = threadIdx.x;
  int virt = xcd_swz();
  int xc = virt & 15;
  int rb = virt >> 4;
  int ry = rb % strip;
  int b = rb / strip;
  int y = s*strip + ry;
  int x0 = xc*16;
  int r = ry + 1;
  if (tid < 255){
    int c0 = 2*tid;
    float wA[9], wB[9], wC[9], wD[9];
    #pragma unroll
    for (int t9 = 0; t9 < 9; t9++){
      wA[t9] = dw_w[c0*9+t9];          wB[t9] = dw_w[(c0+1)*9+t9];
      wC[t9] = dw_w[(c0+HIDC)*9+t9];   wD[t9] = dw_w[(c0+HIDC+1)*9+t9];
    }
    float aA[16], aB[16], aC[16], aD[16];
    {
      float dbA = dw_b[c0], dbB = dw_b[c0+1], dbC = dw_b[c0+HIDC], dbD = dw_b[c0+HIDC+1];
      #pragma unroll
      for (int p = 0; p < 16; p++){ aA[p]=dbA; aB[p]=dbB; aC[p]=dbC; aD[p]=dbD; }
    }
    const u16* Tbase = T + (size_t)(b*trows + r - 1)*NW*HID2C + c0;
    #pragma unroll
    for (int dy = 0; dy < 3; dy++){
      const u16* Tr = Tbase + (size_t)dy*NW*HID2C;
      // input span x0-1 .. x0+16; value at xi feeds outputs p = xi-k with weight dy*3+k
      #pragma unroll
      for (int xi = 0; xi < 18; xi++){
        int xx = x0 - 1 + xi;
        float vA, vB, vC, vD;
        bool guarded = (xi == 0) || (xi == 17);     // only ends can be OOB
        if (!guarded || ((unsigned)xx < (unsigned)NW)){
          const u16* pp = Tr + (size_t)xx*HID2C;
          u32 lo = *(const u32*)pp;
          u32 hi = *(const u32*)(pp + HIDC);
          vA = bf2f((u16)lo); vB = bf2f((u16)(lo>>16));
          vC = bf2f((u16)hi); vD = bf2f((u16)(hi>>16));
        } else { vA = vB = vC = vD = 0.f; }
        #pragma unroll
        for (int k = 0; k < 3; k++){
          int p = xi - k;
          if (p >= 0 && p < 16){
            int wi = dy*3 + k;
            aA[p] += wA[wi]*vA;
            aB[p] += wB[wi]*vB;
            aC[p] += wC[wi]*vC;
            aD[p] += wD[wi]*vD;
          }
        }
      }
    }
    #pragma unroll
    for (int p = 0; p < 16; p++){
      float geA = 0.5f*aA[p]*(1.f + erff(aA[p]*0.70710678118654752f));
      float geB = 0.5f*aB[p]*(1.f + erff(aB[p]*0.70710678118654752f));
      u32 pk = (u32)f2bf(geA*aC[p]) | ((u32)f2bf(geB*aD[p]) << 16);
      *(u32*)&gbuf[p*512 + (c0 ^ ((p&7)<<3))] = pk;
    }
  } else {
    // zero pad channels 510,511 (swizzled)
    #pragma unroll
    for (int p = 0; p < 16; p++) *(u32*)&gbuf[p*512 + (510 ^ ((p&7)<<3))] = 0;
  }
  __syncthreads();

  int wv = tid >> 6, lane = tid & 63;
  int colo = lane & 15, rowg = lane >> 4;
  const bf16x8* gv = (const bf16x8*)gbuf;
  const bf16x8* wv2 = (const bf16x8*)wpk2;
  f32x4 acc0 = {0.f,0.f,0.f,0.f}, acc1 = {0.f,0.f,0.f,0.f}, acc2 = {0.f,0.f,0.f,0.f};
  int nt0 = wv*3;
  for (int ks = 0; ks < 16; ks++){
    bf16x8 a = gv[colo*64 + ((ks*4 + rowg) ^ (colo & 7))];
    const bf16x8* wb = &wv2[(ks*4 + rowg)*192 + colo];
    acc0 = __builtin_amdgcn_mfma_f32_16x16x32_bf16(a, wb[nt0*16],       acc0, 0,0,0);
    acc1 = __builtin_amdgcn_mfma_f32_16x16x32_bf16(a, wb[(nt0+1)*16],   acc1, 0,0,0);
    acc2 = __builtin_amdgcn_mfma_f32_16x16x32_bf16(a, wb[(nt0+2)*16],   acc2, 0,0,0);
  }
  #pragma unroll
  for (int n3 = 0; n3 < 3; n3++){
    f32x4 acc = (n3==0) ? acc0 : (n3==1) ? acc1 : acc2;
    int o = (nt0 + n3)*16 + colo;
    float pb = pout_b[o];
    float v0 = acc[0]+pb, v1 = acc[1]+pb, v2 = acc[2]+pb, v3 = acc[3]+pb;
    ushort4 ov; ov.x = f2bf(v0); ov.y = f2bf(v1); ov.z = f2bf(v2); ov.w = f2bf(v3);
    u16* Gp = G + ((size_t)(b*DIMC + o)*NH + y)*NW + x0 + rowg*4;
    *(ushort4*)Gp = ov;
    float part = v0+v1+v2+v3;
    part += __shfl_xor(part, 16);
    part += __shfl_xor(part, 32);
    if (rowg == 0) atomicAdd(&se_sum[b*DIMC + o], part);
  }
}

// ---------- SE gate vector ----------
__global__ __launch_bounds__(256) void k_se(const float* __restrict__ se_sum,
    const float* __restrict__ w1, const float* __restrict__ w2, float* __restrict__ sey)
{
  __shared__ float mean[NB*DIMC];
  __shared__ float hid[NB*REDC];
  int tid = threadIdx.x;
  for (int i = tid; i < NB*DIMC; i += 256) mean[i] = se_sum[i] * (1.f/(float)HW);
  __syncthreads();
  for (int i = tid; i < NB*REDC; i += 256){
    int b = i / REDC, rr = i % REDC;
    float a = 0.f;
    for (int c = 0; c < DIMC; c++) a += mean[b*DIMC + c]*w1[c*REDC + rr];
    hid[i] = fmaxf(a, 0.f);
  }
  __syncthreads();
  for (int i = tid; i < NB*DIMC; i += 256){
    int b = i / DIMC, o = i % DIMC;
    float a = 0.f;
    for (int rr = 0; rr < REDC; rr++) a += hid[b*REDC + rr]*w2[rr*DIMC + o];
    sey[i] = 1.f/(1.f + expf(-a));
  }
}

// ---------- final: out = x1 + G * sey ----------
__global__ __launch_bounds__(256) void k_final(const u16* __restrict__ G,
    const float* __restrict__ sey, float* __restrict__ xout)
{
  int i4 = blockIdx.x*256 + threadIdx.x;
  int cpix = i4 >> 14;              // b*DIMC + c
  float sc = sey[cpix];
  ushort4 gv = *(const ushort4*)&G[(size_t)i4*4];
  float4 xv = *(const float4*)&xout[(size_t)i4*4];
  float4 ov;
  ov.x = xv.x + bf2f(gv.x)*sc;
  ov.y = xv.y + bf2f(gv.y)*sc;
  ov.z = xv.z + bf2f(gv.z)*sc;
  ov.w = xv.w + bf2f(gv.w)*sc;
  *(float4*)&xout[(size_t)i4*4] = ov;
}

extern "C" void kernel_launch(void* const* d_in, const int* in_sizes, int n_in,
                              void* d_out, int out_size, void* d_ws, size_t ws_size,
                              hipStream_t stream)
{
  const float* x      = (const float*)d_in[0];
  const float* temb   = (const float*)d_in[1];
  const float* gn1_g  = (const float*)d_in[2];
  const float* gn1_b  = (const float*)d_in[3];
  const float* aw1_w1 = (const float*)d_in[4];
  const float* aw1_b1 = (const float*)d_in[5];
  const float* aw1_w2 = (const float*)d_in[6];
  const float* aw1_b2 = (const float*)d_in[7];
  const float* qkv_w  = (const float*)d_in[8];
  const float* qkv_b  = (const float*)d_in[9];
  const float* proj_w = (const float*)d_in[10];
  const float* proj_b = (const float*)d_in[11];
  const float* gn2_g  = (const float*)d_in[12];
  const float* gn2_b  = (const float*)d_in[13];
  const float* aw2_w1 = (const float*)d_in[14];
  const float* aw2_b1 = (const float*)d_in[15];
  const float* aw2_w2 = (const float*)d_in[16];
  const float* aw2_b2 = (const float*)d_in[17];
  const float* pin_w  = (const float*)d_in[18];
  const float* pin_b  = (const float*)d_in[19];
  const float* dw_w   = (const float*)d_in[20];
  const float* dw_b   = (const float*)d_in[21];
  const float* pout_w = (const float*)d_in[22];
  const float* pout_b = (const float*)d_in[23];
  const float* se_w1  = (const float*)d_in[24];
  const float* se_w2  = (const float*)d_in[25];

  unsigned char* ws = (unsigned char*)d_ws;
  // scalars/atomics block (zeroed each launch): 16 doubles + 768 floats = 3200 B
  double* gn1_sum = (double*)ws;
  double* gn1_sq  = gn1_sum + 4;
  double* gn2_sum = gn1_sum + 8;
  double* gn2_sq  = gn1_sum + 12;
  float*  se_sumf = (float*)(ws + 128);
  float*  fbase   = (float*)(ws + 3200);
  float* s1      = fbase;                        // 3072
  float* s2      = s1 + 3072;                    // 3072
  float* stats1  = s2 + 3072;                    // 8
  float* stats2  = stats1 + 8;                   // 8
  float* sey     = stats2 + 8;                   // 768 -> floats end at 30912
  u16* wpk1     = (u16*)(ws + 30976);            // 196608 u16 = 393216 B
  u16* wpk2     = (u16*)(ws + 424192);           // 98304 u16 = 196608 B
  u16* qkv_wpk  = (u16*)(ws + 620800);           // 110592 u16 = 221184 B
  u16* proj_wpk = (u16*)(ws + 841984);           // 36864 u16 = 73728 B -> ends 915712
  size_t offG = 915712;                          // 256-aligned
  u16* G  = (u16*)(ws + offG);                   // 100.7 MB
  size_t offT = offG + (size_t)NB*DIMC*HW*2;
  u16* Tb = (u16*)(ws + offT);

  // pick largest strip that fits the workspace
  int S = 256;
  while (S > 16 && ws_size < offT + (size_t)NB*(S+2)*NW*HID2C*2) S >>= 1;
  int trows = S + 2;
  int nstrips = NH / S;

  float* x1 = (float*)d_out;

  hipMemsetAsync(ws, 0, 3200, stream);
  k_prep<<<768, 256, 0, stream>>>(pin_w, pout_w, qkv_w, proj_w, wpk1, wpk2, qkv_wpk, proj_wpk);
  k_reduce<<<dim3(1024,4), 256, 0, stream>>>(x, gn1_sum, gn1_sq);
  k_stats<<<1, 64, 0, stream>>>(gn1_sum, gn1_sq, stats1);
  k_svec<<<1, 256, 0, stream>>>(temb, aw1_w1, aw1_b1, aw1_w2, aw1_b2, s1);
  k_svec<<<1, 256, 0, stream>>>(temb, aw2_w1, aw2_b1, aw2_w2, aw2_b2, s2);
  k_attn<<<16384, 256, 0, stream>>>(x, stats1, gn1_g, gn1_b, s1,
                                    qkv_wpk, qkv_b, proj_wpk, proj_b, x1, gn2_sum, gn2_sq);
  k_stats<<<1, 64, 0, stream>>>(gn2_sum, gn2_sq, stats2);
  for (int s = 0; s < nstrips; s++){
    k_pin<<<16*trows*NB, 256, 0, stream>>>(x1, stats2, gn2_g, gn2_b, s2,
                                           wpk1, pin_b, Tb, s, S, trows);
    k_dwgate<<<16*S*NB, 256, 0, stream>>>(Tb, wpk2, dw_w, dw_b, pout_b, G, se_sumf, s, S, trows);
  }
  k_se<<<1, 256, 0, stream>>>(se_sumf, se_w1, se_w2, sey);
  k_final<<<49152, 256, 0, stream>>>(G, sey, x1);
}

// Round 6
// 1891.684 us; speedup vs baseline: 15.9476x; 1.0568x over previous
//
#include <hip/hip_runtime.h>
#include <hip/hip_bf16.h>
#include <cmath>

#define DIMC 192
#define NHEAD 6
#define HDIM 32
#define TDIM 128
#define HIDC 510
#define HID2C 1020
#define REDC 24
#define NB 4
#define NH 256
#define NW 256
#define HW 65536
#define NPB (DIMC*HW)

typedef unsigned short u16;
typedef unsigned int u32;
typedef unsigned long long u64;
typedef short bf16x8 __attribute__((ext_vector_type(8)));
typedef float f32x4 __attribute__((ext_vector_type(4)));

__device__ __forceinline__ float bf2f(u16 u){
  union { unsigned int i; float f; } v; v.i = ((unsigned int)u) << 16; return v.f;
}
__device__ __forceinline__ u16 f2bf(float f){
  union { float f; unsigned int i; } v; v.f = f;
  unsigned int i = v.i;
  return (u16)((i + 0x7FFFu + ((i >> 16) & 1u)) >> 16);
}
// XCD-chunked bijective swizzle (requires gridDim.x % 8 == 0)
__device__ __forceinline__ int xcd_swz(){
  int n = gridDim.x, l = blockIdx.x;
  return (l & 7)*(n >> 3) + (l >> 3);
}

// ---------- pack pin_w / pout_w / qkv_w / proj_w into MFMA B-fragment bf16 layouts ----------
// layout: [kscq][o][j], element = W[c = kscq*8 + j][o]
__global__ __launch_bounds__(256) void k_prep(const float* __restrict__ pin_w,
    const float* __restrict__ pout_w, const float* __restrict__ qkv_w,
    const float* __restrict__ proj_w,
    u16* __restrict__ wpk1, u16* __restrict__ wpk2,
    u16* __restrict__ qkv_wpk, u16* __restrict__ proj_wpk)
{
  int i = blockIdx.x*256 + threadIdx.x;
  if (i < 6*4*1024*8){
    int j = i & 7, o = (i >> 3) & 1023, kscq = i >> 13;
    int c = kscq*8 + j;
    wpk1[i] = (o < HID2C) ? f2bf(pin_w[o*DIMC + c]) : (u16)0;
  }
  if (i < 16*4*192*8){
    int j = i & 7, o = (i >> 3) % 192, kscq = (i >> 3) / 192;
    int c = kscq*8 + j;
    wpk2[i] = (c < HIDC) ? f2bf(pout_w[o*HIDC + c]) : (u16)0;
  }
  if (i < 24*576*8){
    int j = i & 7, o = (i >> 3) % 576, kscq = (i >> 3) / 576;
    int c = kscq*8 + j;
    qkv_wpk[i] = f2bf(qkv_w[c*576 + o]);
  }
  if (i < 24*192*8){
    int j = i & 7, o = (i >> 3) % 192, kscq = (i >> 3) / 192;
    int c = kscq*8 + j;
    proj_wpk[i] = f2bf(proj_w[c*192 + o]);
  }
}

// ---------- per-batch sum/sumsq over x ----------
__global__ __launch_bounds__(256) void k_reduce(const float* __restrict__ x,
    double* __restrict__ sum, double* __restrict__ sq)
{
  int b = blockIdx.y;
  const float4* xb = (const float4*)(x + (size_t)b*NPB);
  float ls = 0.f, lq = 0.f;
  int n4 = NPB/4;
  for (int i = blockIdx.x*256 + threadIdx.x; i < n4; i += gridDim.x*256){
    float4 u = xb[i];
    ls += u.x+u.y+u.z+u.w; lq += u.x*u.x + u.y*u.y + u.z*u.z + u.w*u.w;
  }
  __shared__ float rs_[256], rq_[256];
  int tid = threadIdx.x;
  rs_[tid]=ls; rq_[tid]=lq; __syncthreads();
  for (int st=128; st>0; st>>=1){ if (tid<st){ rs_[tid]+=rs_[tid+st]; rq_[tid]+=rq_[tid+st]; } __syncthreads(); }
  if (tid==0){ atomicAdd(&sum[b], (double)rs_[0]); atomicAdd(&sq[b], (double)rq_[0]); }
}

__global__ void k_stats(const double* __restrict__ sum, const double* __restrict__ sq,
                        float* __restrict__ stats)
{
  int t = threadIdx.x;
  if (t < NB){
    double mu = sum[t] / (double)NPB;
    double var = sq[t] / (double)NPB - mu*mu;
    stats[2*t]   = (float)mu;
    stats[2*t+1] = (float)(1.0 / sqrt(var + 1e-5));
  }
}

// ---------- s = silu(temb@w1+b1)@w2+b2 ----------
__global__ __launch_bounds__(256) void k_svec(const float* __restrict__ temb,
    const float* __restrict__ w1, const float* __restrict__ b1,
    const float* __restrict__ w2, const float* __restrict__ b2, float* __restrict__ s)
{
  __shared__ float te[NB*TDIM];
  __shared__ float hid[NB*TDIM];
  int tid = threadIdx.x;
  for (int i = tid; i < NB*TDIM; i += 256) te[i] = temb[i];
  __syncthreads();
  for (int i = tid; i < NB*TDIM; i += 256){
    int b = i >> 7, j = i & 127;
    float a = b1[j];
    for (int c = 0; c < TDIM; c++) a += te[b*TDIM + c]*w1[c*TDIM + j];
    hid[i] = a / (1.f + expf(-a));
  }
  __syncthreads();
  for (int i = tid; i < NB*4*DIMC; i += 256){
    int b = i / 768, o = i % 768;
    float a = b2[o];
    for (int c = 0; c < TDIM; c++) a += hid[b*TDIM + c]*w2[c*768 + o];
    s[i] = a;
  }
}

// ---------- window attention, MFMA qkv/proj, fused gn1+adawm on load ----------
__global__ __launch_bounds__(256) void k_attn(
    const float* __restrict__ x0,
    const float* __restrict__ stats, const float* __restrict__ gg, const float* __restrict__ gb,
    const float* __restrict__ sv,
    const u16* __restrict__ qkv_wpk, const float* __restrict__ qkv_b,
    const u16* __restrict__ proj_wpk, const float* __restrict__ proj_b,
    float* __restrict__ x1out, double* __restrict__ gn2_sum, double* __restrict__ gn2_sq)
{
  __shared__ __align__(16) u16 qkv_bf[16*592];   // [t][o] pitch 592, bf16 (18.9 KB)
  __shared__ __align__(16) u16 xa_bf[3072];      // A-frag tile: xw (phase1-2) then ao (phase3-4)
  float* rs_ = (float*)qkv_bf;                   // epilogue reduction (qkv dead)
  float* rq_ = rs_ + 256;

  int tid = threadIdx.x;
  int blk = xcd_swz();
  int b  = blk >> 12;
  int wy = (blk >> 6) & 63;
  int wx = blk & 63;

  float mu = stats[2*b], rstd = stats[2*b+1];
  const float* sb = sv + b*768;

  // phase 1: load 4x4 window, gn1 + adawm, store as bf16 A-frag (row=token, k=channel)
  for (int l = tid; l < DIMC*4; l += 256){
    int c = l >> 2, q = l & 3;
    int qy = q >> 1, qx = q & 1;
    const float* p = x0 + ((size_t)(b*DIMC + c)*NH + (wy*4 + qy*2))*NW + wx*4 + qx*2;
    float2 t0 = *(const float2*)p;
    float2 t1 = *(const float2*)(p + NW);
    float gc = gg[c], bc = gb[c];
    float n00 = (t0.x-mu)*rstd*gc + bc;
    float n01 = (t0.y-mu)*rstd*gc + bc;
    float n10 = (t1.x-mu)*rstd*gc + bc;
    float n11 = (t1.y-mu)*rstd*gc + bc;
    float ll = (n00+n01+n10+n11)*0.5f*sb[c];
    float hl = (n00-n10+n01-n11)*0.5f*sb[192+c];
    float lh = (n00+n10-n01-n11)*0.5f*sb[384+c];
    float hh = (n00-n10-n01+n11)*0.5f*sb[576+c];
    int cq = c >> 3, j = c & 7;
    int t0i = qy*8 + qx*2;
    xa_bf[(cq*16 + t0i    )*8 + j] = f2bf((ll+hl+lh+hh)*0.5f);
    xa_bf[(cq*16 + t0i + 1)*8 + j] = f2bf((ll+hl-lh-hh)*0.5f);
    xa_bf[(cq*16 + t0i + 4)*8 + j] = f2bf((ll-hl+lh-hh)*0.5f);
    xa_bf[(cq*16 + t0i + 5)*8 + j] = f2bf((ll-hl-lh+hh)*0.5f);
  }
  __syncthreads();

  int wv = tid >> 6, lane = tid & 63;
  int colo = lane & 15, rowg = lane >> 4;

  // phase 2: qkv = xw @ qkv_w + b  (M=16, K=192, N=576; 9 N-tiles per wave)
  {
    const bf16x8* av = (const bf16x8*)xa_bf;
    const bf16x8* bv = (const bf16x8*)qkv_wpk;
    bf16x8 a6[6];
    #pragma unroll
    for (int ks = 0; ks < 6; ks++) a6[ks] = av[(ks*4 + rowg)*16 + colo];
    #pragma unroll
    for (int n3 = 0; n3 < 3; n3++){
      int nt = wv*9 + n3*3;
      f32x4 ac0 = {0.f,0.f,0.f,0.f}, ac1 = {0.f,0.f,0.f,0.f}, ac2 = {0.f,0.f,0.f,0.f};
      #pragma unroll
      for (int ks = 0; ks < 6; ks++){
        const bf16x8* wb = &bv[(ks*4 + rowg)*576 + colo];
        ac0 = __builtin_amdgcn_mfma_f32_16x16x32_bf16(a6[ks], wb[nt*16],     ac0, 0,0,0);
        ac1 = __builtin_amdgcn_mfma_f32_16x16x32_bf16(a6[ks], wb[(nt+1)*16], ac1, 0,0,0);
        ac2 = __builtin_amdgcn_mfma_f32_16x16x32_bf16(a6[ks], wb[(nt+2)*16], ac2, 0,0,0);
      }
      #pragma unroll
      for (int m = 0; m < 3; m++){
        f32x4 ac = (m==0) ? ac0 : (m==1) ? ac1 : ac2;
        int o = (nt+m)*16 + colo;
        float bq = qkv_b[o];
        #pragma unroll
        for (int i = 0; i < 4; i++)
          qkv_bf[(rowg*4 + i)*592 + o] = f2bf(ac[i] + bq);
      }
    }
  }
  __syncthreads();

  // phase 3: attention, 192 threads = (head, q-token, dim-half); shfl_xor(1) completes dots
  if (tid < 192){
    int h = tid / 32, rem = tid % 32, q = rem >> 1, half = rem & 1;
    int cb = h*32 + half*16;
    const u32* qrow = (const u32*)&qkv_bf[q*592 + cb];
    float qv[16];
    #pragma unroll
    for (int m = 0; m < 8; m++){
      u32 u = qrow[m]; qv[2*m] = bf2f((u16)u); qv[2*m+1] = bf2f((u16)(u>>16));
    }
    float sc[16]; float mx = -1e30f;
    for (int kt = 0; kt < 16; kt++){
      const u32* krow = (const u32*)&qkv_bf[kt*592 + 192 + cb];
      float d = 0.f;
      #pragma unroll
      for (int m = 0; m < 8; m++){
        u32 u = krow[m];
        d += qv[2*m]*bf2f((u16)u) + qv[2*m+1]*bf2f((u16)(u>>16));
      }
      d += __shfl_xor(d, 1);
      d *= 0.17677669529663687f;
      sc[kt] = d; mx = fmaxf(mx, d);
    }
    float sum = 0.f;
    #pragma unroll
    for (int kt = 0; kt < 16; kt++){ float e = expf(sc[kt]-mx); sc[kt] = e; sum += e; }
    float inv = 1.f/sum;
    float acc[16];
    #pragma unroll
    for (int m = 0; m < 16; m++) acc[m] = 0.f;
    for (int kt = 0; kt < 16; kt++){
      const u32* vrow = (const u32*)&qkv_bf[kt*592 + 384 + cb];
      float p = sc[kt];
      #pragma unroll
      for (int m = 0; m < 8; m++){
        u32 u = vrow[m];
        acc[2*m]   += p*bf2f((u16)u);
        acc[2*m+1] += p*bf2f((u16)(u>>16));
      }
    }
    // write ao into A-frag layout (aliases dead xw)
    u32* aow = (u32*)xa_bf;
    #pragma unroll
    for (int m = 0; m < 8; m++){
      int c = cb + 2*m;
      int cq = c >> 3, j = c & 7;
      u32 pk = (u32)f2bf(acc[2*m]*inv) | ((u32)f2bf(acc[2*m+1]*inv) << 16);
      aow[((cq*16 + q)*8 + j) >> 1] = pk;
    }
  }
  __syncthreads();

  // phase 4: proj (M=16, K=192, N=192; 3 N-tiles per wave) + residual + gn2 partial
  float lsum = 0.f, lsq = 0.f;
  {
    const bf16x8* av = (const bf16x8*)xa_bf;
    const bf16x8* bv = (const bf16x8*)proj_wpk;
    bf16x8 a6[6];
    #pragma unroll
    for (int ks = 0; ks < 6; ks++) a6[ks] = av[(ks*4 + rowg)*16 + colo];
    int nt = wv*3;
    f32x4 ac0 = {0.f,0.f,0.f,0.f}, ac1 = {0.f,0.f,0.f,0.f}, ac2 = {0.f,0.f,0.f,0.f};
    #pragma unroll
    for (int ks = 0; ks < 6; ks++){
      const bf16x8* wb = &bv[(ks*4 + rowg)*192 + colo];
      ac0 = __builtin_amdgcn_mfma_f32_16x16x32_bf16(a6[ks], wb[nt*16],     ac0, 0,0,0);
      ac1 = __builtin_amdgcn_mfma_f32_16x16x32_bf16(a6[ks], wb[(nt+1)*16], ac1, 0,0,0);
      ac2 = __builtin_amdgcn_mfma_f32_16x16x32_bf16(a6[ks], wb[(nt+2)*16], ac2, 0,0,0);
    }
    int y = wy*4 + rowg;
    #pragma unroll
    for (int m = 0; m < 3; m++){
      f32x4 ac = (m==0) ? ac0 : (m==1) ? ac1 : ac2;
      int o = (nt+m)*16 + colo;
      float pb = proj_b[o];
      size_t addr = ((size_t)(b*DIMC + o)*NH + y)*NW + wx*4;
      float4 xv = *(const float4*)&x0[addr];
      float4 ov;
      ov.x = xv.x + ac[0] + pb;
      ov.y = xv.y + ac[1] + pb;
      ov.z = xv.z + ac[2] + pb;
      ov.w = xv.w + ac[3] + pb;
      *(float4*)&x1out[addr] = ov;
      lsum += ov.x+ov.y+ov.z+ov.w;
      lsq  += ov.x*ov.x + ov.y*ov.y + ov.z*ov.z + ov.w*ov.w;
    }
  }
  rs_[tid] = lsum; rq_[tid] = lsq;
  __syncthreads();
  for (int st = 128; st > 0; st >>= 1){
    if (tid < st){ rs_[tid] += rs_[tid+st]; rq_[tid] += rq_[tid+st]; }
    __syncthreads();
  }
  if (tid == 0){
    atomicAdd(&gn2_sum[b], (double)rs_[0]);
    atomicAdd(&gn2_sq[b], (double)rq_[0]);
  }
}

// ---------- gdfn stage 1: fused gn2+adawm + MFMA pointwise 192->1020 into strip T (bf16)
// LDS union: pxb A-frag (6 KB) during load; Tt[16][1032] u16 output tile (33 KB) after
// epilogue: LDS-staged tile -> 8B contiguous global stores (full-line writes)
__global__ __launch_bounds__(256, 4) void k_pin(
    const float* __restrict__ x1, const float* __restrict__ stats,
    const float* __restrict__ gg, const float* __restrict__ gb, const float* __restrict__ sv,
    const u16* __restrict__ wpk1, const float* __restrict__ pin_b,
    u16* __restrict__ T, int s, int strip, int trows)
{
  __shared__ __align__(16) u16 lds[16*1032];   // 33 KB union
  u16* pxb = lds;                               // phase 1: A-frag tile (3072 u16)
  u16* Tt  = lds;                               // phase 2: output tile [16][1032]
  int tid = threadIdx.x;
  int virt = xcd_swz();
  int xc = virt & 15;
  int rb = virt >> 4;
  int r = rb % trows;
  int b = rb / trows;
  int y = s*strip - 1 + r;
  int x0 = xc*16;
  u16* Trow = T + ((size_t)(b*trows + r)*NW + x0)*HID2C;
  bool valid = (y >= 0) && (y < NH);
  if (!valid){
    u32* Tw = (u32*)Trow;
    for (int l = tid; l < 8*HID2C; l += 256) Tw[l] = 0;
    return;
  }
  float mu = stats[2*b], rstd = stats[2*b+1];
  const float* sb = sv + b*768;
  int ytop = y & ~1;
  bool istop = (y == ytop);
  for (int l = tid; l < DIMC*8; l += 256){
    int c = l >> 3, u = l & 7;
    const float* p = x1 + ((size_t)(b*DIMC + c)*NH + ytop)*NW + x0 + 2*u;
    float2 t0 = *(const float2*)p;
    float2 t1 = *(const float2*)(p + NW);
    float gc = gg[c], bc = gb[c];
    float n00 = (t0.x-mu)*rstd*gc + bc;
    float n01 = (t0.y-mu)*rstd*gc + bc;
    float n10 = (t1.x-mu)*rstd*gc + bc;
    float n11 = (t1.y-mu)*rstd*gc + bc;
    float ll = (n00+n01+n10+n11)*0.5f*sb[c];
    float hl = (n00-n10+n01-n11)*0.5f*sb[192+c];
    float lh = (n00+n10-n01-n11)*0.5f*sb[384+c];
    float hh = (n00-n10-n01+n11)*0.5f*sb[576+c];
    float v0, v1;
    if (istop){ v0 = (ll+hl+lh+hh)*0.5f; v1 = (ll+hl-lh-hh)*0.5f; }
    else      { v0 = (ll-hl+lh-hh)*0.5f; v1 = (ll-hl-lh+hh)*0.5f; }
    int cq = c >> 3, j = c & 7;
    pxb[((cq*16 + 2*u)*8) + j]     = f2bf(v0);
    pxb[((cq*16 + 2*u + 1)*8) + j] = f2bf(v1);
  }
  __syncthreads();

  int wv = tid >> 6, lane = tid & 63;
  int colo = lane & 15, rowg = lane >> 4;
  const bf16x8* pxv = (const bf16x8*)pxb;
  const bf16x8* wv1 = (const bf16x8*)wpk1;
  bf16x8 a6[6];
  #pragma unroll
  for (int ks = 0; ks < 6; ks++)
    a6[ks] = pxv[(ks*4 + rowg)*16 + colo];
  __syncthreads();   // all fragment loads done before Tt overwrites pxb

  for (int nt16 = 0; nt16 < 16; nt16++){
    int nt = wv*16 + nt16;
    f32x4 acc = {0.f, 0.f, 0.f, 0.f};
    #pragma unroll
    for (int ks = 0; ks < 6; ks++)
      acc = __builtin_amdgcn_mfma_f32_16x16x32_bf16(a6[ks],
              wv1[(ks*4 + rowg)*1024 + nt*16 + colo], acc, 0, 0, 0);
    int o = nt*16 + colo;
    if (o < HID2C){
      float pb = pin_b[o];
      #pragma unroll
      for (int i = 0; i < 4; i++)
        Tt[(rowg*4 + i)*1032 + o] = f2bf(acc[i] + pb);
    }
  }
  __syncthreads();

  // writeback: 16 rows x 2040 B, 8B per lane -> wave writes 512 B contiguous
  const u32* Tt32 = (const u32*)Tt;
  for (int idx = tid; idx < 16*255; idx += 256){
    int p = idx / 255, o4 = idx - p*255;
    u64 v = *(const u64*)&Tt32[p*516 + 2*o4];
    *(u64*)&Trow[p*HID2C + 4*o4] = v;
  }
}

// ---------- gdfn stage 2: sliding-window depthwise 3x3 + gelu-gate + MFMA pout 512->192
// gbuf is XOR-swizzled: u16 index p*512 + (c ^ ((p&7)<<3)); read octet (ks*4+rowg)^(colo&7)
__global__ __launch_bounds__(256, 3) void k_dwgate(
    const u16* __restrict__ T, const u16* __restrict__ wpk2,
    const float* __restrict__ dw_w, const float* __restrict__ dw_b,
    const float* __restrict__ pout_b, u16* __restrict__ G,
    float* __restrict__ se_sum, int s, int strip, int trows)
{
  __shared__ __align__(16) u16 gbuf[16*512];   // 16 KB, swizzled [p][c]
  int tid = threadIdx.x;
  int virt = xcd_swz();
  int xc = virt & 15;
  int rb = virt >> 4;
  int ry = rb % strip;
  int b = rb / strip;
  int y = s*strip + ry;
  int x0 = xc*16;
  int r = ry + 1;
  if (tid < 255){
    int c0 = 2*tid;
    float wA[9], wB[9], wC[9], wD[9];
    #pragma unroll
    for (int t9 = 0; t9 < 9; t9++){
      wA[t9] = dw_w[c0*9+t9];          wB[t9] = dw_w[(c0+1)*9+t9];
      wC[t9] = dw_w[(c0+HIDC)*9+t9];   wD[t9] = dw_w[(c0+HIDC+1)*9+t9];
    }
    float aA[16], aB[16], aC[16], aD[16];
    {
      float dbA = dw_b[c0], dbB = dw_b[c0+1], dbC = dw_b[c0+HIDC], dbD = dw_b[c0+HIDC+1];
      #pragma unroll
      for (int p = 0; p < 16; p++){ aA[p]=dbA; aB[p]=dbB; aC[p]=dbC; aD[p]=dbD; }
    }
    const u16* Tbase = T + (size_t)(b*trows + r - 1)*NW*HID2C + c0;
    #pragma unroll
    for (int dy = 0; dy < 3; dy++){
      const u16* Tr = Tbase + (size_t)dy*NW*HID2C;
      // input span x0-1 .. x0+16; value at xi feeds outputs p = xi-k with weight dy*3+k
      #pragma unroll
      for (int xi = 0; xi < 18; xi++){
        int xx = x0 - 1 + xi;
        float vA, vB, vC, vD;
        bool guarded = (xi == 0) || (xi == 17);     // only ends can be OOB
        if (!guarded || ((unsigned)xx < (unsigned)NW)){
          const u16* pp = Tr + (size_t)xx*HID2C;
          u32 lo = *(const u32*)pp;
          u32 hi = *(const u32*)(pp + HIDC);
          vA = bf2f((u16)lo); vB = bf2f((u16)(lo>>16));
          vC = bf2f((u16)hi); vD = bf2f((u16)(hi>>16));
        } else { vA = vB = vC = vD = 0.f; }
        #pragma unroll
        for (int k = 0; k < 3; k++){
          int p = xi - k;
          if (p >= 0 && p < 16){
            int wi = dy*3 + k;
            aA[p] += wA[wi]*vA;
            aB[p] += wB[wi]*vB;
            aC[p] += wC[wi]*vC;
            aD[p] += wD[wi]*vD;
          }
        }
      }
    }
    #pragma unroll
    for (int p = 0; p < 16; p++){
      float geA = 0.5f*aA[p]*(1.f + erff(aA[p]*0.70710678118654752f));
      float geB = 0.5f*aB[p]*(1.f + erff(aB[p]*0.70710678118654752f));
      u32 pk = (u32)f2bf(geA*aC[p]) | ((u32)f2bf(geB*aD[p]) << 16);
      *(u32*)&gbuf[p*512 + (c0 ^ ((p&7)<<3))] = pk;
    }
  } else {
    // zero pad channels 510,511 (swizzled)
    #pragma unroll
    for (int p = 0; p < 16; p++) *(u32*)&gbuf[p*512 + (510 ^ ((p&7)<<3))] = 0;
  }
  __syncthreads();

  int wv = tid >> 6, lane = tid & 63;
  int colo = lane & 15, rowg = lane >> 4;
  const bf16x8* gv = (const bf16x8*)gbuf;
  const bf16x8* wv2 = (const bf16x8*)wpk2;
  f32x4 acc0 = {0.f,0.f,0.f,0.f}, acc1 = {0.f,0.f,0.f,0.f}, acc2 = {0.f,0.f,0.f,0.f};
  int nt0 = wv*3;
  for (int ks = 0; ks < 16; ks++){
    bf16x8 a = gv[colo*64 + ((ks*4 + rowg) ^ (colo & 7))];
    const bf16x8* wb = &wv2[(ks*4 + rowg)*192 + colo];
    acc0 = __builtin_amdgcn_mfma_f32_16x16x32_bf16(a, wb[nt0*16],       acc0, 0,0,0);
    acc1 = __builtin_amdgcn_mfma_f32_16x16x32_bf16(a, wb[(nt0+1)*16],   acc1, 0,0,0);
    acc2 = __builtin_amdgcn_mfma_f32_16x16x32_bf16(a, wb[(nt0+2)*16],   acc2, 0,0,0);
  }
  #pragma unroll
  for (int n3 = 0; n3 < 3; n3++){
    f32x4 acc = (n3==0) ? acc0 : (n3==1) ? acc1 : acc2;
    int o = (nt0 + n3)*16 + colo;
    float pb = pout_b[o];
    float v0 = acc[0]+pb, v1 = acc[1]+pb, v2 = acc[2]+pb, v3 = acc[3]+pb;
    ushort4 ov; ov.x = f2bf(v0); ov.y = f2bf(v1); ov.z = f2bf(v2); ov.w = f2bf(v3);
    u16* Gp = G + ((size_t)(b*DIMC + o)*NH + y)*NW + x0 + rowg*4;
    *(ushort4*)Gp = ov;
    float part = v0+v1+v2+v3;
    part += __shfl_xor(part, 16);
    part += __shfl_xor(part, 32);
    if (rowg == 0) atomicAdd(&se_sum[b*DIMC + o], part);
  }
}

// ---------- SE gate vector ----------
__global__ __launch_bounds__(256) void k_se(const float* __restrict__ se_sum,
    const float* __restrict__ w1, const float* __restrict__ w2, float* __restrict__ sey)
{
  __shared__ float mean[NB*DIMC];
  __shared__ float hid[NB*REDC];
  int tid = threadIdx.x;
  for (int i = tid; i < NB*DIMC; i += 256) mean[i] = se_sum[i] * (1.f/(float)HW);
  __syncthreads();
  for (int i = tid; i < NB*REDC; i += 256){
    int b = i / REDC, rr = i % REDC;
    float a = 0.f;
    for (int c = 0; c < DIMC; c++) a += mean[b*DIMC + c]*w1[c*REDC + rr];
    hid[i] = fmaxf(a, 0.f);
  }
  __syncthreads();
  for (int i = tid; i < NB*DIMC; i += 256){
    int b = i / DIMC, o = i % DIMC;
    float a = 0.f;
    for (int rr = 0; rr < REDC; rr++) a += hid[b*REDC + rr]*w2[rr*DIMC + o];
    sey[i] = 1.f/(1.f + expf(-a));
  }
}

// ---------- final: out = x1 + G * sey ----------
__global__ __launch_bounds__(256) void k_final(const u16* __restrict__ G,
    const float* __restrict__ sey, float* __restrict__ xout)
{
  int i4 = blockIdx.x*256 + threadIdx.x;
  int cpix = i4 >> 14;              // b*DIMC + c
  float sc = sey[cpix];
  ushort4 gv = *(const ushort4*)&G[(size_t)i4*4];
  float4 xv = *(const float4*)&xout[(size_t)i4*4];
  float4 ov;
  ov.x = xv.x + bf2f(gv.x)*sc;
  ov.y = xv.y + bf2f(gv.y)*sc;
  ov.z = xv.z + bf2f(gv.z)*sc;
  ov.w = xv.w + bf2f(gv.w)*sc;
  *(float4*)&xout[(size_t)i4*4] = ov;
}

extern "C" void kernel_launch(void* const* d_in, const int* in_sizes, int n_in,
                              void* d_out, int out_size, void* d_ws, size_t ws_size,
                              hipStream_t stream)
{
  const float* x      = (const float*)d_in[0];
  const float* temb   = (const float*)d_in[1];
  const float* gn1_g  = (const float*)d_in[2];
  const float* gn1_b  = (const float*)d_in[3];
  const float* aw1_w1 = (const float*)d_in[4];
  const float* aw1_b1 = (const float*)d_in[5];
  const float* aw1_w2 = (const float*)d_in[6];
  const float* aw1_b2 = (const float*)d_in[7];
  const float* qkv_w  = (const float*)d_in[8];
  const float* qkv_b  = (const float*)d_in[9];
  const float* proj_w = (const float*)d_in[10];
  const float* proj_b = (const float*)d_in[11];
  const float* gn2_g  = (const float*)d_in[12];
  const float* gn2_b  = (const float*)d_in[13];
  const float* aw2_w1 = (const float*)d_in[14];
  const float* aw2_b1 = (const float*)d_in[15];
  const float* aw2_w2 = (const float*)d_in[16];
  const float* aw2_b2 = (const float*)d_in[17];
  const float* pin_w  = (const float*)d_in[18];
  const float* pin_b  = (const float*)d_in[19];
  const float* dw_w   = (const float*)d_in[20];
  const float* dw_b   = (const float*)d_in[21];
  const float* pout_w = (const float*)d_in[22];
  const float* pout_b = (const float*)d_in[23];
  const float* se_w1  = (const float*)d_in[24];
  const float* se_w2  = (const float*)d_in[25];

  unsigned char* ws = (unsigned char*)d_ws;
  // scalars/atomics block (zeroed each launch): 16 doubles + 768 floats = 3200 B
  double* gn1_sum = (double*)ws;
  double* gn1_sq  = gn1_sum + 4;
  double* gn2_sum = gn1_sum + 8;
  double* gn2_sq  = gn1_sum + 12;
  float*  se_sumf = (float*)(ws + 128);
  float*  fbase   = (float*)(ws + 3200);
  float* s1      = fbase;                        // 3072
  float* s2      = s1 + 3072;                    // 3072
  float* stats1  = s2 + 3072;                    // 8
  float* stats2  = stats1 + 8;                   // 8
  float* sey     = stats2 + 8;                   // 768 -> floats end at 30912
  u16* wpk1     = (u16*)(ws + 30976);            // 196608 u16 = 393216 B
  u16* wpk2     = (u16*)(ws + 424192);           // 98304 u16 = 196608 B
  u16* qkv_wpk  = (u16*)(ws + 620800);           // 110592 u16 = 221184 B
  u16* proj_wpk = (u16*)(ws + 841984);           // 36864 u16 = 73728 B -> ends 915712
  size_t offG = 915712;                          // 256-aligned
  u16* G  = (u16*)(ws + offG);                   // 100.7 MB
  size_t offT = offG + (size_t)NB*DIMC*HW*2;
  u16* Tb = (u16*)(ws + offT);

  // pick largest strip that fits the workspace
  int S = 256;
  while (S > 16 && ws_size < offT + (size_t)NB*(S+2)*NW*HID2C*2) S >>= 1;
  int trows = S + 2;
  int nstrips = NH / S;

  float* x1 = (float*)d_out;

  hipMemsetAsync(ws, 0, 3200, stream);
  k_prep<<<768, 256, 0, stream>>>(pin_w, pout_w, qkv_w, proj_w, wpk1, wpk2, qkv_wpk, proj_wpk);
  k_reduce<<<dim3(1024,4), 256, 0, stream>>>(x, gn1_sum, gn1_sq);
  k_stats<<<1, 64, 0, stream>>>(gn1_sum, gn1_sq, stats1);
  k_svec<<<1, 256, 0, stream>>>(temb, aw1_w1, aw1_b1, aw1_w2, aw1_b2, s1);
  k_svec<<<1, 256, 0, stream>>>(temb, aw2_w1, aw2_b1, aw2_w2, aw2_b2, s2);
  k_attn<<<16384, 256, 0, stream>>>(x, stats1, gn1_g, gn1_b, s1,
                                    qkv_wpk, qkv_b, proj_wpk, proj_b, x1, gn2_sum, gn2_sq);
  k_stats<<<1, 64, 0, stream>>>(gn2_sum, gn2_sq, stats2);
  for (int s = 0; s < nstrips; s++){
    k_pin<<<16*trows*NB, 256, 0, stream>>>(x1, stats2, gn2_g, gn2_b, s2,
                                           wpk1, pin_b, Tb, s, S, trows);
    k_dwgate<<<16*S*NB, 256, 0, stream>>>(Tb, wpk2, dw_w, dw_b, pout_b, G, se_sumf, s, S, trows);
  }
  k_se<<<1, 256, 0, stream>>>(se_sumf, se_w1, se_w2, sey);
  k_final<<<49152, 256, 0, stream>>>(G, sey, x1);
}